// Round 2
// baseline (559.470 us; speedup 1.0000x reference)
//
#include <hip/hip_runtime.h>
#include <hip/hip_bf16.h>
#include <math.h>

typedef __bf16 bf16;
typedef bf16 bf16x2 __attribute__((ext_vector_type(2)));
typedef bf16 bf16x4 __attribute__((ext_vector_type(4)));
typedef bf16 bf16x8 __attribute__((ext_vector_type(8)));
typedef float f32x4 __attribute__((ext_vector_type(4)));

#define T_TOK 4096
#define DDIM  768
#define HDIM  2688
#define NEXP  8
#define RMAX  10240           // max padded pair rows (8192 + 8*255 rounded up to 256)
#define NMT   (RMAX / 128)    // 80 mtiles for gemm2
#define NMT1  (RMAX / 256)    // 40 mtiles for gemm1
#define NT1G  (HDIM / 128)    // 21 n-tiles for gemm1
#define NT2   (DDIM / 128)    // 6
#define KHALF (HDIM / 2)      // 1344
#define NKT1  (DDIM / 64)     // 12 K-tiles for gemm1

__device__ __forceinline__ void async_copy16(const void* g, void* l) {
    __builtin_amdgcn_global_load_lds(
        (__attribute__((address_space(1))) void*)g,
        (__attribute__((address_space(3))) void*)l,
        16, 0, 0);
}

#define LGKM0 do { asm volatile("s_waitcnt lgkmcnt(0)" ::: "memory"); __builtin_amdgcn_sched_barrier(0); } while(0)
#define VM0   asm volatile("s_waitcnt vmcnt(0)" ::: "memory")
#define BAR   __builtin_amdgcn_s_barrier()

// ---------------- Router ----------------
__global__ void router_kernel(const float* __restrict__ x,
                              const float* __restrict__ gate_w,
                              const float* __restrict__ ebias,
                              int* __restrict__ ctrl,
                              int* __restrict__ tok_e,
                              float* __restrict__ tok_w,
                              float* __restrict__ zloss) {
    __shared__ float gw[NEXP * DDIM];
    int tid = threadIdx.x;
    for (int i = tid; i < NEXP * DDIM / 4; i += 256)
        ((float4*)gw)[i] = ((const float4*)gate_w)[i];
    __syncthreads();

    int wv = tid >> 6, lane = tid & 63;
    int t = blockIdx.x * 4 + wv;
    const float* xr = x + (size_t)t * DDIM;

    float4 xv[3];
#pragma unroll
    for (int j = 0; j < 3; ++j) xv[j] = ((const float4*)xr)[j * 64 + lane];

    float acc[NEXP];
#pragma unroll
    for (int e = 0; e < NEXP; ++e) {
        float a = 0.f;
#pragma unroll
        for (int j = 0; j < 3; ++j) {
            float4 w = ((const float4*)(gw + e * DDIM))[j * 64 + lane];
            a += xv[j].x * w.x + xv[j].y * w.y + xv[j].z * w.z + xv[j].w * w.w;
        }
        acc[e] = a;
    }
#pragma unroll
    for (int e = 0; e < NEXP; ++e) {
#pragma unroll
        for (int off = 32; off > 0; off >>= 1) acc[e] += __shfl_xor(acc[e], off);
    }

    if (lane == 0) {
        float b[NEXP];
#pragma unroll
        for (int e = 0; e < NEXP; ++e) b[e] = acc[e] + ebias[e];
        int i0 = 0;
#pragma unroll
        for (int e = 1; e < NEXP; ++e) if (b[e] > b[i0]) i0 = e;
        int i1 = (i0 == 0) ? 1 : 0;
        float b1 = b[i1];
#pragma unroll
        for (int e = 0; e < NEXP; ++e) if (e != i0 && b[e] > b1) { b1 = b[e]; i1 = e; }

        float l0 = acc[i0], l1 = acc[i1];
        float mx = fmaxf(l0, l1);
        float e0 = __expf(l0 - mx), e1 = __expf(l1 - mx);
        float inv = 1.f / (e0 + e1);
        tok_e[t * 2 + 0] = i0;
        tok_e[t * 2 + 1] = i1;
        tok_w[t * 2 + 0] = e0 * inv;
        tok_w[t * 2 + 1] = e1 * inv;
        atomicAdd(&ctrl[i0], 1);
        atomicAdd(&ctrl[i1], 1);

        float m8 = acc[0];
#pragma unroll
        for (int e = 1; e < NEXP; ++e) m8 = fmaxf(m8, acc[e]);
        float s = 0.f;
#pragma unroll
        for (int e = 0; e < NEXP; ++e) s += __expf(acc[e] - m8);
        float lse = m8 + __logf(s);
        atomicAdd(zloss, (1e-5f / (float)T_TOK) * lse * lse);
    }
}

__global__ void offsets_kernel(int* ctrl) {
    if (threadIdx.x == 0 && blockIdx.x == 0) {
        int off = 0;
        for (int e = 0; e < NEXP; ++e) {
            ctrl[16 + e] = off;
            off += (ctrl[e] + 255) & ~255;   // pad experts to 256 rows for gemm1 tiles
        }
        ctrl[16 + NEXP] = off;
    }
}

__global__ void scatter_kernel(int* __restrict__ ctrl,
                               const int* __restrict__ tok_e,
                               const float* __restrict__ tok_w,
                               int* __restrict__ pair_tok,
                               int* __restrict__ tok_pos) {
    int t = blockIdx.x * 256 + threadIdx.x;
    if (t >= T_TOK) return;
#pragma unroll
    for (int k = 0; k < 2; ++k) {
        int e = tok_e[t * 2 + k];
        int pos = ctrl[16 + e] + atomicAdd(&ctrl[8 + e], 1);
        pair_tok[pos] = t;
        tok_pos[t * 2 + k] = pos;
    }
}

__global__ void gather_kernel(const float* __restrict__ x,
                              const int* __restrict__ ctrl,
                              const int* __restrict__ pair_tok,
                              bf16* __restrict__ Xg) {
    int r = blockIdx.x;
    int tid = threadIdx.x;  // 192 threads, 4 floats each
    const int* offs = ctrl + 16;
    int total = offs[8];
    int tok = -1;
    if (r < total) {
        int e = 0;
#pragma unroll
        for (int i = 1; i < NEXP; ++i) if (r >= offs[i]) e = i;
        if (r - offs[e] < ctrl[e]) tok = pair_tok[r];
    }
    bf16x4 o;
    if (tok >= 0) {
        float4 v = *(const float4*)(x + (size_t)tok * DDIM + tid * 4);
        o.x = (bf16)v.x; o.y = (bf16)v.y; o.z = (bf16)v.z; o.w = (bf16)v.w;
    } else {
        o.x = (bf16)0.f; o.y = (bf16)0.f; o.z = (bf16)0.f; o.w = (bf16)0.f;
    }
    *(bf16x4*)(Xg + (size_t)r * DDIM + tid * 4) = o;
}

// ---------------- Weight transpose fp32->bf16 ----------------
__global__ void transpose_kernel(const float* __restrict__ wgp,
                                 const float* __restrict__ wup,
                                 const float* __restrict__ wdp,
                                 bf16* __restrict__ WgT,
                                 bf16* __restrict__ WuT,
                                 bf16* __restrict__ WdT) {
    __shared__ float tile[64 * 64];
    int m = blockIdx.y;
    int kind = m >> 3, e = m & 7;
    const float* src; bf16* dst; int R, C;
    if (kind == 0)      { src = wgp + (size_t)e * DDIM * HDIM; dst = WgT + (size_t)e * HDIM * DDIM; R = DDIM; C = HDIM; }
    else if (kind == 1) { src = wup + (size_t)e * DDIM * HDIM; dst = WuT + (size_t)e * HDIM * DDIM; R = DDIM; C = HDIM; }
    else                { src = wdp + (size_t)e * HDIM * DDIM; dst = WdT + (size_t)e * DDIM * HDIM; R = HDIM; C = DDIM; }

    int nR = R >> 6;
    int t = blockIdx.x;
    int tr = t % nR, tc = t / nR;
    int r0 = tr << 6, c0 = tc << 6;
    int tid = threadIdx.x;

#pragma unroll
    for (int i = 0; i < 4; ++i) {
        int idx = i * 256 + tid;
        int rr = idx >> 4, c4 = idx & 15;
        int cs = c4 ^ ((rr >> 3) & 3);
        float4 v = *(const float4*)(src + (size_t)(r0 + rr) * C + c0 + c4 * 4);
        *(float4*)&tile[rr * 64 + cs * 4] = v;
    }
    __syncthreads();

#pragma unroll
    for (int i = 0; i < 2; ++i) {
        int idx = i * 256 + tid;
        int cc = idx >> 3, rp0 = (idx & 7) * 8;
        bf16x8 o;
#pragma unroll
        for (int j = 0; j < 8; ++j) {
            int r = rp0 + j;
            o[j] = (bf16)tile[r * 64 + (((cc >> 2) ^ ((r >> 3) & 3)) << 2) + (cc & 3)];
        }
        *(bf16x8*)(dst + (size_t)(c0 + cc) * R + r0 + rp0) = o;
    }
}

// ---------------- GEMM1 (8-phase style): G = silu(Xg@Wg) * (Xg@Wu) ----------------
// BM=256 rows, N-tile = 128 gate + 128 up cols, BK=64, 8 waves (2M x 4N), 128 KiB dbuf LDS.
// B LDS rows per wn-quadrant: [0..31]=gate cols wn*32.., [32..63]=up cols wn*32.. -> SwiGLU pairs intra-thread.
__launch_bounds__(512, 2)
__global__ void gemm1_kernel(const bf16* __restrict__ Xg,
                             const bf16* __restrict__ WgT,
                             const bf16* __restrict__ WuT,
                             const int* __restrict__ ctrl,
                             bf16* __restrict__ G) {
    extern __shared__ __align__(16) bf16 smem[];   // 65536 elems = 128 KiB

    int bid = blockIdx.x;
    int id = (bid & 7) * (NMT1 * NT1G / 8) + (bid >> 3);   // XCD swizzle, 840 % 8 == 0
    int gm = id / NT1G, nt = id % NT1G;
    const int* offs = ctrl + 16;
    int row0 = gm * 256;
    if (row0 >= offs[NEXP]) return;
    int e = 0;
#pragma unroll
    for (int i = 1; i < NEXP; ++i) if (row0 >= offs[i]) e = i;
    int n0 = nt * 128;

    int tid = threadIdx.x;
    int wv = tid >> 6, lane = tid & 63;
    int wm = wv & 1, wn = wv >> 1;
    int quad = lane >> 4, lm = lane & 15;

    // ---- staging sources: 8 x 16B chunks per thread per K-tile (A 4, B 4) ----
    // chunk c (16B) of A-tile: r = c>>3 (lds row), q = c&7; source k-chunk = q ^ (r&7)
    const bf16* srcA[4];
    const bf16* srcB[4];
#pragma unroll
    for (int j = 0; j < 4; ++j) {
        int c = j * 512 + tid;
        int r = c >> 3, q = c & 7;
        srcA[j] = Xg + (size_t)(row0 + r) * DDIM + (q ^ (r & 7)) * 8;
        int q4 = r >> 6, rr = r & 63;
        const bf16* base = (rr < 32)
            ? (WgT + ((size_t)e * HDIM + n0 + q4 * 32 + rr) * DDIM)
            : (WuT + ((size_t)e * HDIM + n0 + q4 * 32 + (rr - 32)) * DDIM);
        srcB[j] = base + (q ^ (r & 7)) * 8;
    }

#define STAGE1(KT, TB) do { \
    int ko_ = (KT) * 64; \
    _Pragma("unroll") for (int j_ = 0; j_ < 4; ++j_) { \
        async_copy16(srcA[j_] + ko_, smem + (TB) * 32768 + j_ * 4096 + tid * 8); \
        async_copy16(srcB[j_] + ko_, smem + (TB) * 32768 + 16384 + j_ * 4096 + tid * 8); \
    } } while (0)

    // ---- fragment read bases (elems); swizzle key = lm&7 on 8-elem chunks ----
    int aBase = (wm * 128 + lm) * 64;
    int bBase = 16384 + (wn * 64 + lm) * 64;
    int cA = (quad ^ (lm & 7)) * 8;          // ks0 chunk; ks1 = cA ^ 32

    f32x4 acc[8][4];
#pragma unroll
    for (int mi = 0; mi < 8; ++mi)
#pragma unroll
        for (int nf = 0; nf < 4; ++nf) acc[mi][nf] = 0.f;

    bf16x8 af[4][2], bb[4][2];

#define RD_AF(M2, MB, SB) do { \
    af[M2][0] = *(const bf16x8*)((SB) + aBase + ((MB) + (M2)) * 1024 + cA); \
    af[M2][1] = *(const bf16x8*)((SB) + aBase + ((MB) + (M2)) * 1024 + (cA ^ 32)); } while (0)
#define RD_BF(NF, SB) do { \
    bb[NF][0] = *(const bf16x8*)((SB) + bBase + (NF) * 1024 + cA); \
    bb[NF][1] = *(const bf16x8*)((SB) + bBase + (NF) * 1024 + (cA ^ 32)); } while (0)
#define MMQ(MA, NA) \
    _Pragma("unroll") for (int m2_ = 0; m2_ < 4; ++m2_) \
    _Pragma("unroll") for (int n2_ = 0; n2_ < 2; ++n2_) \
    _Pragma("unroll") for (int ks_ = 0; ks_ < 2; ++ks_) \
        acc[(MA) + m2_][(NA) + n2_] = __builtin_amdgcn_mfma_f32_16x16x32_bf16( \
            af[m2_][ks_], bb[(NA) + n2_][ks_], acc[(MA) + m2_][(NA) + n2_], 0, 0, 0);

    // prologue: stage tile 0 into buf 0, drain, sync
    STAGE1(0, 0);
    VM0;
    BAR;

#pragma unroll
    for (int kt = 0; kt < NKT1; ++kt) {
        const int buf = kt & 1;
        const bf16* sbuf = smem + buf * 32768;
        if (kt + 1 < NKT1) STAGE1(kt + 1, buf ^ 1);   // prefetch next tile (other buffer)

        // P1: A mi0-3 + B gate (nf0-1) -> 16 MFMA
        RD_AF(0, 0, sbuf); RD_AF(1, 0, sbuf); RD_AF(2, 0, sbuf); RD_AF(3, 0, sbuf);
        RD_BF(0, sbuf); RD_BF(1, sbuf);
        BAR; LGKM0;
        __builtin_amdgcn_s_setprio(1); MMQ(0, 0); __builtin_amdgcn_s_setprio(0);
        BAR;
        // P2: B up (nf2-3) -> 16 MFMA (af mi0-3 kept)
        RD_BF(2, sbuf); RD_BF(3, sbuf);
        BAR; LGKM0;
        __builtin_amdgcn_s_setprio(1); MMQ(0, 2); __builtin_amdgcn_s_setprio(0);
        BAR;
        // P3: A mi4-7 -> 16 MFMA with up (bb2-3 kept)
        RD_AF(0, 4, sbuf); RD_AF(1, 4, sbuf); RD_AF(2, 4, sbuf); RD_AF(3, 4, sbuf);
        BAR; LGKM0;
        __builtin_amdgcn_s_setprio(1); MMQ(4, 2); __builtin_amdgcn_s_setprio(0);
        BAR;
        // P4: reg-only: mi4-7 x gate (bb0-1 kept)
        __builtin_amdgcn_s_setprio(1); MMQ(4, 0); __builtin_amdgcn_s_setprio(0);
        // tile end: wait prefetch arrived (issued ~3 phases ago), then cross-wave order
        VM0;
        BAR;
    }

    // ---- epilogue: SwiGLU + LDS repack (4 slabs of 64 rows), coalesced bf16x8 stores ----
#pragma unroll
    for (int s = 0; s < 4; ++s) {
        if (wm == (s >> 1)) {
#pragma unroll
            for (int m2 = 0; m2 < 4; ++m2) {
                const int mi = (s & 1) * 4 + m2;
#pragma unroll
                for (int nj = 0; nj < 2; ++nj) {
#pragma unroll
                    for (int r = 0; r < 4; ++r) {
                        float gg = acc[mi][nj][r];
                        float uu = acc[mi][nj + 2][r];
                        float val = (gg / (1.f + __expf(-gg))) * uu;
                        int lr = m2 * 16 + quad * 4 + r;
                        int col = wn * 32 + nj * 16 + lm;
                        smem[lr * 136 + col] = (bf16)val;
                    }
                }
            }
        }
        __syncthreads();
#pragma unroll
        for (int v = 0; v < 2; ++v) {
            int idx = v * 512 + tid;
            int rw = idx >> 4, c8 = idx & 15;
            bf16x8 vec = *(const bf16x8*)(smem + rw * 136 + c8 * 8);
            *(bf16x8*)(G + (size_t)(row0 + s * 64 + rw) * HDIM + n0 + c8 * 8) = vec;
        }
        if (s < 3) __syncthreads();
    }
#undef STAGE1
#undef RD_AF
#undef RD_BF
#undef MMQ
}

// ---------------- GEMM2: Y_s = G[:, s*1344:(s+1)*1344] @ Wd[s half], bf16 partials ----------------
__launch_bounds__(256)
__global__ void gemm2_kernel(const bf16* __restrict__ G,
                             const bf16* __restrict__ WdT,
                             const int* __restrict__ ctrl,
                             bf16* __restrict__ Ya,
                             bf16* __restrict__ Yb) {
    int id = blockIdx.x;
    int gm = id / (NT2 * 2);
    int r2 = id % (NT2 * 2);
    int nt = r2 >> 1, s = r2 & 1;
    const int* offs = ctrl + 16;
    int row0 = gm * 128;
    if (row0 >= offs[NEXP]) return;
    int e = 0;
#pragma unroll
    for (int i = 1; i < NEXP; ++i) if (row0 >= offs[i]) e = i;
    int n0 = nt * 128;

    __shared__ __align__(16) bf16 smem[16384];   // sA 2x4096 | sB 2x4096
    bf16* sA = smem;
    bf16* sB = smem + 8192;

    int tid = threadIdx.x;
    int wv = tid >> 6, lane = tid & 63;
    int wm = wv & 1, wn = wv >> 1;
    int quad = lane >> 4, lm = lane & 15;

    int arow = tid >> 2, aseg = tid & 3;
    int kc = (aseg ^ ((arow >> 1) & 3)) * 8;
    size_t aoff = (size_t)arow * HDIM + kc + s * KHALF;

    const bf16* Ab = G + (size_t)row0 * HDIM + aoff;
    const bf16* A2 = Ab + (size_t)64 * HDIM;
    const bf16* Bb = WdT + ((size_t)e * DDIM + n0) * HDIM + aoff;
    const bf16* B2 = Bb + (size_t)64 * HDIM;

    bf16* dA  = sA + (size_t)tid * 8;
    bf16* dA2 = dA + 2048;
    bf16* dB  = sB + (size_t)tid * 8;
    bf16* dB2 = dB + 2048;

    int swq = quad ^ ((lm >> 1) & 3);
    const bf16* fa = sA + (wm * 64 + lm) * 32 + swq * 8;
    const bf16* fb = sB + (wn * 64 + lm) * 32 + swq * 8;

    f32x4 acc[4][4];
#pragma unroll
    for (int mi = 0; mi < 4; ++mi)
#pragma unroll
        for (int ni = 0; ni < 4; ++ni) acc[mi][ni] = 0.f;

    async_copy16(Ab, dA);
    async_copy16(A2, dA2);
    async_copy16(Bb, dB);
    async_copy16(B2, dB2);

    const int NK = KHALF / 32;  // 42
#pragma unroll
    for (int ks = 0; ks < NK; ++ks) {
        __syncthreads();
        if (ks + 1 < NK) {
            int kk = (ks + 1) * 32;
            int bo = ((ks + 1) & 1) ? 1 : 0;
            async_copy16(Ab + kk, dA + bo * 4096);
            async_copy16(A2 + kk, dA2 + bo * 4096);
            async_copy16(Bb + kk, dB + bo * 4096);
            async_copy16(B2 + kk, dB2 + bo * 4096);
        }
        int buf = ks & 1;
        bf16x8 af[4], bbf[4];
#pragma unroll
        for (int mi = 0; mi < 4; ++mi)
            af[mi] = *(const bf16x8*)(fa + buf * 4096 + mi * 16 * 32);
#pragma unroll
        for (int ni = 0; ni < 4; ++ni)
            bbf[ni] = *(const bf16x8*)(fb + buf * 4096 + ni * 16 * 32);
#pragma unroll
        for (int mi = 0; mi < 4; ++mi)
#pragma unroll
            for (int ni = 0; ni < 4; ++ni)
                acc[mi][ni] = __builtin_amdgcn_mfma_f32_16x16x32_bf16(af[mi], bbf[ni], acc[mi][ni], 0, 0, 0);
    }

    bf16* Y = s ? Yb : Ya;
    __syncthreads();
#pragma unroll
    for (int rr = 0; rr < 2; ++rr) {
#pragma unroll
        for (int mi = 0; mi < 4; ++mi)
#pragma unroll
            for (int nj = 0; nj < 2; ++nj) {
                int ni = rr * 2 + nj;
#pragma unroll
                for (int r = 0; r < 4; ++r) {
                    int rl = wm * 64 + mi * 16 + quad * 4 + r;
                    int c  = wn * 32 + nj * 16 + lm;
                    smem[rl * 72 + c] = (bf16)acc[mi][ni][r];
                }
            }
        __syncthreads();
#pragma unroll
        for (int i = 0; i < 4; ++i) {
            int idx = (i * 256 + tid) * 8;
            int row = idx >> 6, c = idx & 63;
            bf16x8 v = *(const bf16x8*)(smem + row * 72 + c);
            int col = n0 + ((c >> 5) << 6) + (c & 31) + rr * 32;
            *(bf16x8*)(Y + (size_t)(row0 + row) * DDIM + col) = v;
        }
        if (rr == 0) __syncthreads();
    }
}

// ---------------- Combine ----------------
__global__ void combine_kernel(const bf16* __restrict__ Ya,
                               const bf16* __restrict__ Yb,
                               const int* __restrict__ tok_pos,
                               const float* __restrict__ tok_w,
                               float* __restrict__ out) {
    int t = blockIdx.x;
    int i = threadIdx.x;           // 192 threads x 4 cols
    int p0 = tok_pos[t * 2 + 0], p1 = tok_pos[t * 2 + 1];
    float w0 = tok_w[t * 2 + 0], w1 = tok_w[t * 2 + 1];
    bf16x4 a0 = *(const bf16x4*)(Ya + (size_t)p0 * DDIM + i * 4);
    bf16x4 b0 = *(const bf16x4*)(Yb + (size_t)p0 * DDIM + i * 4);
    bf16x4 a1 = *(const bf16x4*)(Ya + (size_t)p1 * DDIM + i * 4);
    bf16x4 b1 = *(const bf16x4*)(Yb + (size_t)p1 * DDIM + i * 4);
    float4 o;
    o.x = w0 * ((float)a0.x + (float)b0.x) + w1 * ((float)a1.x + (float)b1.x);
    o.y = w0 * ((float)a0.y + (float)b0.y) + w1 * ((float)a1.y + (float)b1.y);
    o.z = w0 * ((float)a0.z + (float)b0.z) + w1 * ((float)a1.z + (float)b1.z);
    o.w = w0 * ((float)a0.w + (float)b0.w) + w1 * ((float)a1.w + (float)b1.w);
    *(float4*)(out + (size_t)t * DDIM + i * 4) = o;
}

extern "C" void kernel_launch(void* const* d_in, const int* in_sizes, int n_in,
                              void* d_out, int out_size, void* d_ws, size_t ws_size,
                              hipStream_t stream) {
    const float* x      = (const float*)d_in[0];
    const float* gate_w = (const float*)d_in[1];
    const float* ebias  = (const float*)d_in[2];
    const float* wgp    = (const float*)d_in[3];
    const float* wup    = (const float*)d_in[4];
    const float* wdp    = (const float*)d_in[5];
    float* out = (float*)d_out;

    int*   ctrl     = (int*)d_ws;                          // 128 ints
    int*   tok_e    = ctrl + 128;                          // 2T
    float* tok_w    = (float*)(tok_e + 2 * T_TOK);         // 2T
    int*   pair_tok = (int*)(tok_w + 2 * T_TOK);           // RMAX
    int*   tok_pos  = pair_tok + RMAX;                     // 2T
    bf16*  Xg       = (bf16*)(tok_pos + 2 * T_TOK);        // RMAX*768 (reused as Ya)
    bf16*  Ya       = Xg;
    bf16*  Yb       = Xg + (size_t)RMAX * DDIM;            // RMAX*768
    bf16*  G        = Yb + (size_t)RMAX * DDIM;            // RMAX*2688
    bf16*  WgT      = G + (size_t)RMAX * HDIM;
    bf16*  WuT      = WgT + (size_t)NEXP * DDIM * HDIM;
    bf16*  WdT      = WuT + (size_t)NEXP * DDIM * HDIM;

    hipMemsetAsync(out + (size_t)T_TOK * DDIM, 0, sizeof(float), stream);  // z_loss
    hipMemsetAsync(d_ws, 0, 512, stream);                                  // ctrl

    router_kernel<<<T_TOK / 4, 256, 0, stream>>>(x, gate_w, ebias, ctrl, tok_e, tok_w,
                                                 out + (size_t)T_TOK * DDIM);
    offsets_kernel<<<1, 64, 0, stream>>>(ctrl);
    scatter_kernel<<<T_TOK / 256, 256, 0, stream>>>(ctrl, tok_e, tok_w, pair_tok, tok_pos);
    transpose_kernel<<<dim3(504, 24), 256, 0, stream>>>(wgp, wup, wdp, WgT, WuT, WdT);
    gather_kernel<<<RMAX, 192, 0, stream>>>(x, ctrl, pair_tok, Xg);
    gemm1_kernel<<<NMT1 * NT1G, 512, 131072, stream>>>(Xg, WgT, WuT, ctrl, G);
    gemm2_kernel<<<NMT * NT2 * 2, 256, 0, stream>>>(G, WdT, ctrl, Ya, Yb);
    combine_kernel<<<T_TOK, 192, 0, stream>>>(Ya, Yb, tok_pos, tok_w, out);
}

// Round 3
// 511.613 us; speedup vs baseline: 1.0935x; 1.0935x over previous
//
#include <hip/hip_runtime.h>
#include <hip/hip_bf16.h>
#include <math.h>

typedef __bf16 bf16;
typedef bf16 bf16x2 __attribute__((ext_vector_type(2)));
typedef bf16 bf16x4 __attribute__((ext_vector_type(4)));
typedef bf16 bf16x8 __attribute__((ext_vector_type(8)));
typedef float f32x4 __attribute__((ext_vector_type(4)));

#define T_TOK 4096
#define DDIM  768
#define HDIM  2688
#define NEXP  8
#define RMAX  9216            // max padded pair rows (8192 + 8*127 rounded up)
#define NMT   (RMAX / 128)    // 72 mtiles
#define NT1   (HDIM / 64)     // 42 n-tiles gemm1
#define NT2   (DDIM / 128)    // 6 n-tiles gemm2
#define KHALF (HDIM / 2)      // 1344
#define NK1   (DDIM / 64)     // 12 K-tiles gemm1
#define NK2   (KHALF / 64)    // 21 K-tiles gemm2

__device__ __forceinline__ void async_copy16(const void* g, void* l) {
    __builtin_amdgcn_global_load_lds(
        (__attribute__((address_space(1))) void*)g,
        (__attribute__((address_space(3))) void*)l,
        16, 0, 0);
}

#define LGKM0 do { asm volatile("s_waitcnt lgkmcnt(0)" ::: "memory"); __builtin_amdgcn_sched_barrier(0); } while(0)
#define VMC4  asm volatile("s_waitcnt vmcnt(4)" ::: "memory")
#define VMC0  asm volatile("s_waitcnt vmcnt(0)" ::: "memory")
#define BAR   __builtin_amdgcn_s_barrier()

// ---------------- Router ----------------
__global__ void router_kernel(const float* __restrict__ x,
                              const float* __restrict__ gate_w,
                              const float* __restrict__ ebias,
                              int* __restrict__ ctrl,
                              int* __restrict__ tok_e,
                              float* __restrict__ tok_w,
                              float* __restrict__ zloss) {
    __shared__ float gw[NEXP * DDIM];
    int tid = threadIdx.x;
    for (int i = tid; i < NEXP * DDIM / 4; i += 256)
        ((float4*)gw)[i] = ((const float4*)gate_w)[i];
    __syncthreads();

    int wv = tid >> 6, lane = tid & 63;
    int t = blockIdx.x * 4 + wv;
    const float* xr = x + (size_t)t * DDIM;

    float4 xv[3];
#pragma unroll
    for (int j = 0; j < 3; ++j) xv[j] = ((const float4*)xr)[j * 64 + lane];

    float acc[NEXP];
#pragma unroll
    for (int e = 0; e < NEXP; ++e) {
        float a = 0.f;
#pragma unroll
        for (int j = 0; j < 3; ++j) {
            float4 w = ((const float4*)(gw + e * DDIM))[j * 64 + lane];
            a += xv[j].x * w.x + xv[j].y * w.y + xv[j].z * w.z + xv[j].w * w.w;
        }
        acc[e] = a;
    }
#pragma unroll
    for (int e = 0; e < NEXP; ++e) {
#pragma unroll
        for (int off = 32; off > 0; off >>= 1) acc[e] += __shfl_xor(acc[e], off);
    }

    if (lane == 0) {
        float b[NEXP];
#pragma unroll
        for (int e = 0; e < NEXP; ++e) b[e] = acc[e] + ebias[e];
        int i0 = 0;
#pragma unroll
        for (int e = 1; e < NEXP; ++e) if (b[e] > b[i0]) i0 = e;
        int i1 = (i0 == 0) ? 1 : 0;
        float b1 = b[i1];
#pragma unroll
        for (int e = 0; e < NEXP; ++e) if (e != i0 && b[e] > b1) { b1 = b[e]; i1 = e; }

        float l0 = acc[i0], l1 = acc[i1];
        float mx = fmaxf(l0, l1);
        float e0 = __expf(l0 - mx), e1 = __expf(l1 - mx);
        float inv = 1.f / (e0 + e1);
        tok_e[t * 2 + 0] = i0;
        tok_e[t * 2 + 1] = i1;
        tok_w[t * 2 + 0] = e0 * inv;
        tok_w[t * 2 + 1] = e1 * inv;
        atomicAdd(&ctrl[i0], 1);
        atomicAdd(&ctrl[i1], 1);

        float m8 = acc[0];
#pragma unroll
        for (int e = 1; e < NEXP; ++e) m8 = fmaxf(m8, acc[e]);
        float s = 0.f;
#pragma unroll
        for (int e = 0; e < NEXP; ++e) s += __expf(acc[e] - m8);
        float lse = m8 + __logf(s);
        atomicAdd(zloss, (1e-5f / (float)T_TOK) * lse * lse);
    }
}

__global__ void offsets_kernel(int* ctrl) {
    if (threadIdx.x == 0 && blockIdx.x == 0) {
        int off = 0;
        for (int e = 0; e < NEXP; ++e) {
            ctrl[16 + e] = off;
            off += (ctrl[e] + 127) & ~127;
        }
        ctrl[16 + NEXP] = off;
    }
}

__global__ void scatter_kernel(int* __restrict__ ctrl,
                               const int* __restrict__ tok_e,
                               const float* __restrict__ tok_w,
                               int* __restrict__ pair_tok,
                               int* __restrict__ tok_pos) {
    int t = blockIdx.x * 256 + threadIdx.x;
    if (t >= T_TOK) return;
#pragma unroll
    for (int k = 0; k < 2; ++k) {
        int e = tok_e[t * 2 + k];
        int pos = ctrl[16 + e] + atomicAdd(&ctrl[8 + e], 1);
        pair_tok[pos] = t;
        tok_pos[t * 2 + k] = pos;
    }
}

__global__ void gather_kernel(const float* __restrict__ x,
                              const int* __restrict__ ctrl,
                              const int* __restrict__ pair_tok,
                              bf16* __restrict__ Xg) {
    int r = blockIdx.x;
    int tid = threadIdx.x;  // 192 threads, 4 floats each
    const int* offs = ctrl + 16;
    int total = offs[8];
    int tok = -1;
    if (r < total) {
        int e = 0;
#pragma unroll
        for (int i = 1; i < NEXP; ++i) if (r >= offs[i]) e = i;
        if (r - offs[e] < ctrl[e]) tok = pair_tok[r];
    }
    bf16x4 o;
    if (tok >= 0) {
        float4 v = *(const float4*)(x + (size_t)tok * DDIM + tid * 4);
        o.x = (bf16)v.x; o.y = (bf16)v.y; o.z = (bf16)v.z; o.w = (bf16)v.w;
    } else {
        o.x = (bf16)0.f; o.y = (bf16)0.f; o.z = (bf16)0.f; o.w = (bf16)0.f;
    }
    *(bf16x4*)(Xg + (size_t)r * DDIM + tid * 4) = o;
}

// ---------------- Weight transpose fp32->bf16 ----------------
__global__ void transpose_kernel(const float* __restrict__ wgp,
                                 const float* __restrict__ wup,
                                 const float* __restrict__ wdp,
                                 bf16* __restrict__ WgT,
                                 bf16* __restrict__ WuT,
                                 bf16* __restrict__ WdT) {
    __shared__ float tile[64 * 64];
    int m = blockIdx.y;
    int kind = m >> 3, e = m & 7;
    const float* src; bf16* dst; int R, C;
    if (kind == 0)      { src = wgp + (size_t)e * DDIM * HDIM; dst = WgT + (size_t)e * HDIM * DDIM; R = DDIM; C = HDIM; }
    else if (kind == 1) { src = wup + (size_t)e * DDIM * HDIM; dst = WuT + (size_t)e * HDIM * DDIM; R = DDIM; C = HDIM; }
    else                { src = wdp + (size_t)e * HDIM * DDIM; dst = WdT + (size_t)e * DDIM * HDIM; R = HDIM; C = DDIM; }

    int nR = R >> 6;
    int t = blockIdx.x;
    int tr = t % nR, tc = t / nR;
    int r0 = tr << 6, c0 = tc << 6;
    int tid = threadIdx.x;

#pragma unroll
    for (int i = 0; i < 4; ++i) {
        int idx = i * 256 + tid;
        int rr = idx >> 4, c4 = idx & 15;
        int cs = c4 ^ ((rr >> 3) & 3);
        float4 v = *(const float4*)(src + (size_t)(r0 + rr) * C + c0 + c4 * 4);
        *(float4*)&tile[rr * 64 + cs * 4] = v;
    }
    __syncthreads();

#pragma unroll
    for (int i = 0; i < 2; ++i) {
        int idx = i * 256 + tid;
        int cc = idx >> 3, rp0 = (idx & 7) * 8;
        bf16x8 o;
#pragma unroll
        for (int j = 0; j < 8; ++j) {
            int r = rp0 + j;
            o[j] = (bf16)tile[r * 64 + (((cc >> 2) ^ ((r >> 3) & 3)) << 2) + (cc & 3)];
        }
        *(bf16x8*)(dst + (size_t)(c0 + cc) * R + r0 + rp0) = o;
    }
}

// ---------------- GEMM1: G = silu(Xg@Wg) * (Xg@Wu) ----------------
// 128 rows x (64 gate + 64 up) cols, BK=64, dbuf, counted vmcnt, 2 barriers/K-tile.
// LDS 64 KiB -> 2 blocks/CU for cross-block latency hiding.
__launch_bounds__(256)
__global__ void gemm1_kernel(const bf16* __restrict__ Xg,
                             const bf16* __restrict__ WgT,
                             const bf16* __restrict__ WuT,
                             const int* __restrict__ ctrl,
                             bf16* __restrict__ G) {
    extern __shared__ __align__(16) bf16 smem[];   // 32768 elems: A[2][8192] | B[2][8192]

    int bid = blockIdx.x;
    int id = (bid & 7) * (NMT * NT1 / 8) + (bid >> 3);   // XCD swizzle; 3024 % 8 == 0
    int gm = id / NT1, nt = id % NT1;
    const int* offs = ctrl + 16;
    int row0 = gm * 128;
    if (row0 >= offs[NEXP]) return;
    int e = 0;
#pragma unroll
    for (int i = 1; i < NEXP; ++i) if (row0 >= offs[i]) e = i;
    int n0 = nt * 64;

    int tid = threadIdx.x;
    int wv = tid >> 6, lane = tid & 63;
    int wm = wv & 1, wn = wv >> 1;
    int quad = lane >> 4, lm = lane & 15;

    // staging sources: per thread 4 chunks A + 4 chunks B per K-tile.
    // chunk c: LDS row r=c>>3, slot q=c&7 holds global k-chunk q^(r&7)  (involution)
    const bf16* srcA[4];
    const bf16* srcB[4];
#pragma unroll
    for (int j = 0; j < 4; ++j) {
        int c = j * 256 + tid;
        int r = c >> 3, q = c & 7;
        srcA[j] = Xg + (size_t)(row0 + r) * DDIM + (q ^ (r & 7)) * 8;
        const bf16* wb = (j < 2) ? (WgT + ((size_t)e * HDIM + n0 + r) * DDIM)
                                 : (WuT + ((size_t)e * HDIM + n0 + (r - 64)) * DDIM);
        srcB[j] = wb + (q ^ (r & 7)) * 8;
    }

#define STG_A1(KT, BUF) do { int ko_ = (KT) * 64; \
    _Pragma("unroll") for (int j_ = 0; j_ < 4; ++j_) \
        async_copy16(srcA[j_] + ko_, smem + (BUF) * 8192 + (j_ * 256 + tid) * 8); } while (0)
#define STG_B1(KT, BUF) do { int ko_ = (KT) * 64; \
    _Pragma("unroll") for (int j_ = 0; j_ < 4; ++j_) \
        async_copy16(srcB[j_] + ko_, smem + 16384 + (BUF) * 8192 + (j_ * 256 + tid) * 8); } while (0)

    // fragment bases (elems): row stride 64; chunk cA = swizzled slot for quad; ks1 -> cA^32
    int aOff = (wm * 64 + lm) * 64;
    int bOff = (wn * 32 + lm) * 64;      // gate rows 0..63; up rows +64 (=+4096 elems)
    int cA = (quad ^ (lm & 7)) * 8;

    f32x4 accg[4][2], accu[4][2];
#pragma unroll
    for (int mi = 0; mi < 4; ++mi)
#pragma unroll
        for (int nf = 0; nf < 2; ++nf) { accg[mi][nf] = 0.f; accu[mi][nf] = 0.f; }

    STG_A1(0, 0);
    STG_B1(0, 0);

#pragma unroll
    for (int kt = 0; kt < NK1; ++kt) {
        const int buf = kt & 1;
        const bf16* pa = smem + buf * 8192;
        const bf16* pb = smem + 16384 + buf * 8192;
        if (kt + 1 < NK1) { STG_A1(kt + 1, buf ^ 1); VMC4; }   // waits tile-kt's 8 loads only
        else              { VMC0; }
        BAR;

        bf16x8 af[4][2], bbg[2][2], bbu[2][2];
#pragma unroll
        for (int mi = 0; mi < 4; ++mi)
#pragma unroll
            for (int ks = 0; ks < 2; ++ks)
                af[mi][ks] = *(const bf16x8*)(pa + aOff + mi * 1024 + (cA ^ (ks * 32)));
#pragma unroll
        for (int nf = 0; nf < 2; ++nf)
#pragma unroll
            for (int ks = 0; ks < 2; ++ks)
                bbg[nf][ks] = *(const bf16x8*)(pb + bOff + nf * 1024 + (cA ^ (ks * 32)));
        LGKM0;
        __builtin_amdgcn_s_setprio(1);
#pragma unroll
        for (int mi = 0; mi < 4; ++mi)
#pragma unroll
            for (int nf = 0; nf < 2; ++nf)
#pragma unroll
                for (int ks = 0; ks < 2; ++ks)
                    accg[mi][nf] = __builtin_amdgcn_mfma_f32_16x16x32_bf16(af[mi][ks], bbg[nf][ks], accg[mi][nf], 0, 0, 0);
        __builtin_amdgcn_s_setprio(0);

        if (kt + 1 < NK1) STG_B1(kt + 1, buf ^ 1);   // issue B prefetch mid-tile

#pragma unroll
        for (int nf = 0; nf < 2; ++nf)
#pragma unroll
            for (int ks = 0; ks < 2; ++ks)
                bbu[nf][ks] = *(const bf16x8*)(pb + 4096 + bOff + nf * 1024 + (cA ^ (ks * 32)));
        LGKM0;
        __builtin_amdgcn_s_setprio(1);
#pragma unroll
        for (int mi = 0; mi < 4; ++mi)
#pragma unroll
            for (int nf = 0; nf < 2; ++nf)
#pragma unroll
                for (int ks = 0; ks < 2; ++ks)
                    accu[mi][nf] = __builtin_amdgcn_mfma_f32_16x16x32_bf16(af[mi][ks], bbu[nf][ks], accu[mi][nf], 0, 0, 0);
        __builtin_amdgcn_s_setprio(0);
        BAR;   // all waves done reading buf; next iter may overwrite buf^1... / buf
    }

    // epilogue: SwiGLU + LDS repack -> coalesced bf16x8 stores
#pragma unroll
    for (int mi = 0; mi < 4; ++mi)
#pragma unroll
        for (int nj = 0; nj < 2; ++nj)
#pragma unroll
            for (int r = 0; r < 4; ++r) {
                float gg = accg[mi][nj][r];
                float u = accu[mi][nj][r];
                float val = (gg / (1.f + __expf(-gg))) * u;
                int rl = wm * 64 + mi * 16 + quad * 4 + r;
                int c  = wn * 32 + nj * 16 + lm;
                smem[rl * 72 + c] = (bf16)val;
            }
    __syncthreads();
#pragma unroll
    for (int i = 0; i < 4; ++i) {
        int idx = (i * 256 + tid) * 8;
        int row = idx >> 6, c = idx & 63;
        bf16x8 v = *(const bf16x8*)(smem + row * 72 + c);
        *(bf16x8*)(G + (size_t)(row0 + row) * HDIM + n0 + c) = v;
    }
#undef STG_A1
#undef STG_B1
}

// ---------------- GEMM2: Y_s = G[:, s*1344:(s+1)*1344] @ Wd[s half] ----------------
// Same schedule as gemm1: 128x128 tile, BK=64, counted vmcnt, 2 barriers/K-tile, 64 KiB LDS.
__launch_bounds__(256)
__global__ void gemm2_kernel(const bf16* __restrict__ G,
                             const bf16* __restrict__ WdT,
                             const int* __restrict__ ctrl,
                             bf16* __restrict__ Ya,
                             bf16* __restrict__ Yb) {
    extern __shared__ __align__(16) bf16 smem[];   // 32768 elems: A[2][8192] | B[2][8192]

    int bid = blockIdx.x;
    int id = (bid & 7) * (NMT * NT2 * 2 / 8) + (bid >> 3);   // 864 % 8 == 0
    int gm = id / (NT2 * 2);
    int r2 = id % (NT2 * 2);
    int nt = r2 >> 1, s = r2 & 1;
    const int* offs = ctrl + 16;
    int row0 = gm * 128;
    if (row0 >= offs[NEXP]) return;
    int e = 0;
#pragma unroll
    for (int i = 1; i < NEXP; ++i) if (row0 >= offs[i]) e = i;
    int n0 = nt * 128;

    int tid = threadIdx.x;
    int wv = tid >> 6, lane = tid & 63;
    int wm = wv & 1, wn = wv >> 1;
    int quad = lane >> 4, lm = lane & 15;

    const bf16* srcA[4];
    const bf16* srcB[4];
#pragma unroll
    for (int j = 0; j < 4; ++j) {
        int c = j * 256 + tid;
        int r = c >> 3, q = c & 7;
        srcA[j] = G + (size_t)(row0 + r) * HDIM + s * KHALF + (q ^ (r & 7)) * 8;
        srcB[j] = WdT + ((size_t)e * DDIM + n0 + r) * HDIM + s * KHALF + (q ^ (r & 7)) * 8;
    }

#define STG_A2(KT, BUF) do { int ko_ = (KT) * 64; \
    _Pragma("unroll") for (int j_ = 0; j_ < 4; ++j_) \
        async_copy16(srcA[j_] + ko_, smem + (BUF) * 8192 + (j_ * 256 + tid) * 8); } while (0)
#define STG_B2(KT, BUF) do { int ko_ = (KT) * 64; \
    _Pragma("unroll") for (int j_ = 0; j_ < 4; ++j_) \
        async_copy16(srcB[j_] + ko_, smem + 16384 + (BUF) * 8192 + (j_ * 256 + tid) * 8); } while (0)

    int aOff = (wm * 64 + lm) * 64;
    int bOff = (wn * 64 + lm) * 64;      // B rows 0..127, wave wn owns rows wn*64..
    int cA = (quad ^ (lm & 7)) * 8;

    f32x4 acc[4][4];
#pragma unroll
    for (int mi = 0; mi < 4; ++mi)
#pragma unroll
        for (int nf = 0; nf < 4; ++nf) acc[mi][nf] = 0.f;

    STG_A2(0, 0);
    STG_B2(0, 0);

#pragma unroll
    for (int kt = 0; kt < NK2; ++kt) {
        const int buf = kt & 1;
        const bf16* pa = smem + buf * 8192;
        const bf16* pb = smem + 16384 + buf * 8192;
        if (kt + 1 < NK2) { STG_A2(kt + 1, buf ^ 1); VMC4; }
        else              { VMC0; }
        BAR;

        bf16x8 af[4][2], bb[4][2];
#pragma unroll
        for (int mi = 0; mi < 4; ++mi)
#pragma unroll
            for (int ks = 0; ks < 2; ++ks)
                af[mi][ks] = *(const bf16x8*)(pa + aOff + mi * 1024 + (cA ^ (ks * 32)));
#pragma unroll
        for (int nf = 0; nf < 2; ++nf)
#pragma unroll
            for (int ks = 0; ks < 2; ++ks)
                bb[nf][ks] = *(const bf16x8*)(pb + bOff + nf * 1024 + (cA ^ (ks * 32)));
        LGKM0;
        __builtin_amdgcn_s_setprio(1);
#pragma unroll
        for (int mi = 0; mi < 4; ++mi)
#pragma unroll
            for (int nf = 0; nf < 2; ++nf)
#pragma unroll
                for (int ks = 0; ks < 2; ++ks)
                    acc[mi][nf] = __builtin_amdgcn_mfma_f32_16x16x32_bf16(af[mi][ks], bb[nf][ks], acc[mi][nf], 0, 0, 0);
        __builtin_amdgcn_s_setprio(0);

        if (kt + 1 < NK2) STG_B2(kt + 1, buf ^ 1);

#pragma unroll
        for (int nf = 2; nf < 4; ++nf)
#pragma unroll
            for (int ks = 0; ks < 2; ++ks)
                bb[nf][ks] = *(const bf16x8*)(pb + bOff + nf * 1024 + (cA ^ (ks * 32)));
        LGKM0;
        __builtin_amdgcn_s_setprio(1);
#pragma unroll
        for (int mi = 0; mi < 4; ++mi)
#pragma unroll
            for (int nf = 2; nf < 4; ++nf)
#pragma unroll
                for (int ks = 0; ks < 2; ++ks)
                    acc[mi][nf] = __builtin_amdgcn_mfma_f32_16x16x32_bf16(af[mi][ks], bb[nf][ks], acc[mi][nf], 0, 0, 0);
        __builtin_amdgcn_s_setprio(0);
        BAR;
    }

    // epilogue: two rounds of LDS repack -> coalesced bf16x8 stores
    bf16* Y = s ? Yb : Ya;
#pragma unroll
    for (int rr = 0; rr < 2; ++rr) {
#pragma unroll
        for (int mi = 0; mi < 4; ++mi)
#pragma unroll
            for (int nj = 0; nj < 2; ++nj) {
                int ni = rr * 2 + nj;
#pragma unroll
                for (int r = 0; r < 4; ++r) {
                    int rl = wm * 64 + mi * 16 + quad * 4 + r;
                    int c  = wn * 32 + nj * 16 + lm;
                    smem[rl * 72 + c] = (bf16)acc[mi][ni][r];
                }
            }
        __syncthreads();
#pragma unroll
        for (int i = 0; i < 4; ++i) {
            int idx = (i * 256 + tid) * 8;
            int row = idx >> 6, c = idx & 63;
            bf16x8 v = *(const bf16x8*)(smem + row * 72 + c);
            int col = n0 + ((c >> 5) << 6) + (c & 31) + rr * 32;
            *(bf16x8*)(Y + (size_t)(row0 + row) * DDIM + col) = v;
        }
        if (rr == 0) __syncthreads();
    }
#undef STG_A2
#undef STG_B2
}

// ---------------- Combine ----------------
__global__ void combine_kernel(const bf16* __restrict__ Ya,
                               const bf16* __restrict__ Yb,
                               const int* __restrict__ tok_pos,
                               const float* __restrict__ tok_w,
                               float* __restrict__ out) {
    int t = blockIdx.x;
    int i = threadIdx.x;           // 192 threads x 4 cols
    int p0 = tok_pos[t * 2 + 0], p1 = tok_pos[t * 2 + 1];
    float w0 = tok_w[t * 2 + 0], w1 = tok_w[t * 2 + 1];
    bf16x4 a0 = *(const bf16x4*)(Ya + (size_t)p0 * DDIM + i * 4);
    bf16x4 b0 = *(const bf16x4*)(Yb + (size_t)p0 * DDIM + i * 4);
    bf16x4 a1 = *(const bf16x4*)(Ya + (size_t)p1 * DDIM + i * 4);
    bf16x4 b1 = *(const bf16x4*)(Yb + (size_t)p1 * DDIM + i * 4);
    float4 o;
    o.x = w0 * ((float)a0.x + (float)b0.x) + w1 * ((float)a1.x + (float)b1.x);
    o.y = w0 * ((float)a0.y + (float)b0.y) + w1 * ((float)a1.y + (float)b1.y);
    o.z = w0 * ((float)a0.z + (float)b0.z) + w1 * ((float)a1.z + (float)b1.z);
    o.w = w0 * ((float)a0.w + (float)b0.w) + w1 * ((float)a1.w + (float)b1.w);
    *(float4*)(out + (size_t)t * DDIM + i * 4) = o;
}

extern "C" void kernel_launch(void* const* d_in, const int* in_sizes, int n_in,
                              void* d_out, int out_size, void* d_ws, size_t ws_size,
                              hipStream_t stream) {
    const float* x      = (const float*)d_in[0];
    const float* gate_w = (const float*)d_in[1];
    const float* ebias  = (const float*)d_in[2];
    const float* wgp    = (const float*)d_in[3];
    const float* wup    = (const float*)d_in[4];
    const float* wdp    = (const float*)d_in[5];
    float* out = (float*)d_out;

    int*   ctrl     = (int*)d_ws;                          // 128 ints
    int*   tok_e    = ctrl + 128;                          // 2T
    float* tok_w    = (float*)(tok_e + 2 * T_TOK);         // 2T
    int*   pair_tok = (int*)(tok_w + 2 * T_TOK);           // RMAX
    int*   tok_pos  = pair_tok + RMAX;                     // 2T
    bf16*  Xg       = (bf16*)(tok_pos + 2 * T_TOK);        // RMAX*768 (reused as Ya)
    bf16*  Ya       = Xg;
    bf16*  Yb       = Xg + (size_t)RMAX * DDIM;            // RMAX*768
    bf16*  G        = Yb + (size_t)RMAX * DDIM;            // RMAX*2688
    bf16*  WgT      = G + (size_t)RMAX * HDIM;
    bf16*  WuT      = WgT + (size_t)NEXP * DDIM * HDIM;
    bf16*  WdT      = WuT + (size_t)NEXP * DDIM * HDIM;

    hipMemsetAsync(out + (size_t)T_TOK * DDIM, 0, sizeof(float), stream);  // z_loss
    hipMemsetAsync(d_ws, 0, 512, stream);                                  // ctrl

    router_kernel<<<T_TOK / 4, 256, 0, stream>>>(x, gate_w, ebias, ctrl, tok_e, tok_w,
                                                 out + (size_t)T_TOK * DDIM);
    offsets_kernel<<<1, 64, 0, stream>>>(ctrl);
    scatter_kernel<<<T_TOK / 256, 256, 0, stream>>>(ctrl, tok_e, tok_w, pair_tok, tok_pos);
    transpose_kernel<<<dim3(504, 24), 256, 0, stream>>>(wgp, wup, wdp, WgT, WuT, WdT);
    gather_kernel<<<RMAX, 192, 0, stream>>>(x, ctrl, pair_tok, Xg);
    gemm1_kernel<<<NMT * NT1, 256, 65536, stream>>>(Xg, WgT, WuT, ctrl, G);
    gemm2_kernel<<<NMT * NT2 * 2, 256, 65536, stream>>>(G, WdT, ctrl, Ya, Yb);
    combine_kernel<<<T_TOK, 192, 0, stream>>>(Ya, Yb, tok_pos, tok_w, out);
}

// Round 4
// 384.036 us; speedup vs baseline: 1.4568x; 1.3322x over previous
//
#include <hip/hip_runtime.h>
#include <hip/hip_bf16.h>
#include <math.h>

typedef __bf16 bf16;
typedef bf16 bf16x2 __attribute__((ext_vector_type(2)));
typedef bf16 bf16x4 __attribute__((ext_vector_type(4)));
typedef bf16 bf16x8 __attribute__((ext_vector_type(8)));
typedef float f32x4 __attribute__((ext_vector_type(4)));

#define T_TOK 4096
#define DDIM  768
#define HDIM  2688
#define NEXP  8
#define RMAX  9216            // max padded pair rows (8192 + 8*127 rounded up)
#define NMT   (RMAX / 128)    // 72 mtiles
#define NT1   (HDIM / 64)     // 42 n-tiles gemm1
#define NT2   (DDIM / 128)    // 6 n-tiles gemm2
#define KHALF (HDIM / 2)      // 1344
#define NK1   (DDIM / 64)     // 12 K-tiles gemm1
#define NK2   (KHALF / 64)    // 21 K-tiles gemm2
#define RBLK  (T_TOK / 4)     // 1024 router blocks

__device__ __forceinline__ void async_copy16(const void* g, void* l) {
    __builtin_amdgcn_global_load_lds(
        (__attribute__((address_space(1))) void*)g,
        (__attribute__((address_space(3))) void*)l,
        16, 0, 0);
}

#define LGKM0 do { asm volatile("s_waitcnt lgkmcnt(0)" ::: "memory"); __builtin_amdgcn_sched_barrier(0); } while(0)
#define VMC4  asm volatile("s_waitcnt vmcnt(4)" ::: "memory")
#define VMC0  asm volatile("s_waitcnt vmcnt(0)" ::: "memory")
#define BAR   __builtin_amdgcn_s_barrier()

// ---------------- Router: logits, top-2, per-block histogram + lse2 partials ----------------
// NO global atomics (the 103us same-cacheline atomic storm was the dispatch-drain bottleneck).
__global__ void router_kernel(const float* __restrict__ x,
                              const float* __restrict__ gate_w,
                              const float* __restrict__ ebias,
                              int* __restrict__ tok_e,
                              float* __restrict__ tok_w,
                              int* __restrict__ cpart,
                              float* __restrict__ zpart) {
    __shared__ float gw[NEXP * DDIM];
    __shared__ int hist[NEXP];
    __shared__ float z4[4];
    int tid = threadIdx.x;
    if (tid < NEXP) hist[tid] = 0;
    for (int i = tid; i < NEXP * DDIM / 4; i += 256)
        ((float4*)gw)[i] = ((const float4*)gate_w)[i];
    __syncthreads();

    int wv = tid >> 6, lane = tid & 63;
    int t = blockIdx.x * 4 + wv;
    const float* xr = x + (size_t)t * DDIM;

    float4 xv[3];
#pragma unroll
    for (int j = 0; j < 3; ++j) xv[j] = ((const float4*)xr)[j * 64 + lane];

    float acc[NEXP];
#pragma unroll
    for (int e = 0; e < NEXP; ++e) {
        float a = 0.f;
#pragma unroll
        for (int j = 0; j < 3; ++j) {
            float4 w = ((const float4*)(gw + e * DDIM))[j * 64 + lane];
            a += xv[j].x * w.x + xv[j].y * w.y + xv[j].z * w.z + xv[j].w * w.w;
        }
        acc[e] = a;
    }
#pragma unroll
    for (int e = 0; e < NEXP; ++e) {
#pragma unroll
        for (int off = 32; off > 0; off >>= 1) acc[e] += __shfl_xor(acc[e], off);
    }

    if (lane == 0) {
        float b[NEXP];
#pragma unroll
        for (int e = 0; e < NEXP; ++e) b[e] = acc[e] + ebias[e];
        int i0 = 0;
#pragma unroll
        for (int e = 1; e < NEXP; ++e) if (b[e] > b[i0]) i0 = e;
        int i1 = (i0 == 0) ? 1 : 0;
        float b1 = b[i1];
#pragma unroll
        for (int e = 0; e < NEXP; ++e) if (e != i0 && b[e] > b1) { b1 = b[e]; i1 = e; }

        float l0 = acc[i0], l1 = acc[i1];
        float mx = fmaxf(l0, l1);
        float e0 = __expf(l0 - mx), e1 = __expf(l1 - mx);
        float inv = 1.f / (e0 + e1);
        tok_e[t * 2 + 0] = i0;
        tok_e[t * 2 + 1] = i1;
        tok_w[t * 2 + 0] = e0 * inv;
        tok_w[t * 2 + 1] = e1 * inv;
        atomicAdd(&hist[i0], 1);   // LDS atomic — cheap
        atomicAdd(&hist[i1], 1);

        float m8 = acc[0];
#pragma unroll
        for (int e = 1; e < NEXP; ++e) m8 = fmaxf(m8, acc[e]);
        float s = 0.f;
#pragma unroll
        for (int e = 0; e < NEXP; ++e) s += __expf(acc[e] - m8);
        float lse = m8 + __logf(s);
        z4[wv] = lse * lse;
    }
    __syncthreads();
    if (tid < NEXP) cpart[blockIdx.x * NEXP + tid] = hist[tid];
    if (tid == NEXP) zpart[blockIdx.x] = z4[0] + z4[1] + z4[2] + z4[3];
}

// ---------------- Setup: reduce partials -> counts/offsets/zloss, then scatter via LDS counters ----
__global__ void setup_kernel(int* __restrict__ ctrl,
                             const int* __restrict__ cpart,
                             const float* __restrict__ zpart,
                             const int* __restrict__ tok_e,
                             int* __restrict__ pair_tok,
                             int* __restrict__ tok_pos,
                             float* __restrict__ zloss) {
    __shared__ int whist[16][NEXP];
    __shared__ float wz[16];
    __shared__ int scnt[NEXP];
    int tid = threadIdx.x;              // 1024 threads = 16 waves
    int wv = tid >> 6, lane = tid & 63;

    int h[NEXP];
#pragma unroll
    for (int e = 0; e < NEXP; ++e) h[e] = cpart[tid * NEXP + e];
    float z = zpart[tid];
#pragma unroll
    for (int off = 32; off > 0; off >>= 1) {
#pragma unroll
        for (int e = 0; e < NEXP; ++e) h[e] += __shfl_xor(h[e], off);
        z += __shfl_xor(z, off);
    }
    if (lane == 0) {
#pragma unroll
        for (int e = 0; e < NEXP; ++e) whist[wv][e] = h[e];
        wz[wv] = z;
    }
    __syncthreads();
    if (tid == 0) {
        float zs = 0.f;
        for (int w = 0; w < 16; ++w) zs += wz[w];
        *zloss = (1e-5f / (float)T_TOK) * zs;
        int off = 0;
        for (int e = 0; e < NEXP; ++e) {
            int c = 0;
            for (int w = 0; w < 16; ++w) c += whist[w][e];
            ctrl[e] = c;
            ctrl[16 + e] = off;
            scnt[e] = off;
            off += (c + 127) & ~127;
        }
        ctrl[16 + NEXP] = off;
    }
    __syncthreads();
    // scatter: any bijection within each expert's range is valid (combine uses tok_pos).
    for (int t = tid; t < T_TOK; t += 1024) {
#pragma unroll
        for (int k = 0; k < 2; ++k) {
            int e = tok_e[t * 2 + k];
            int pos = atomicAdd(&scnt[e], 1);   // LDS atomic
            pair_tok[pos] = t;
            tok_pos[t * 2 + k] = pos;
        }
    }
}

__global__ void gather_kernel(const float* __restrict__ x,
                              const int* __restrict__ ctrl,
                              const int* __restrict__ pair_tok,
                              bf16* __restrict__ Xg) {
    int r = blockIdx.x;
    int tid = threadIdx.x;  // 192 threads, 4 floats each
    const int* offs = ctrl + 16;
    int total = offs[8];
    int tok = -1;
    if (r < total) {
        int e = 0;
#pragma unroll
        for (int i = 1; i < NEXP; ++i) if (r >= offs[i]) e = i;
        if (r - offs[e] < ctrl[e]) tok = pair_tok[r];
    }
    bf16x4 o;
    if (tok >= 0) {
        float4 v = *(const float4*)(x + (size_t)tok * DDIM + tid * 4);
        o.x = (bf16)v.x; o.y = (bf16)v.y; o.z = (bf16)v.z; o.w = (bf16)v.w;
    } else {
        o.x = (bf16)0.f; o.y = (bf16)0.f; o.z = (bf16)0.f; o.w = (bf16)0.f;
    }
    *(bf16x4*)(Xg + (size_t)r * DDIM + tid * 4) = o;
}

// ---------------- Weight transpose fp32->bf16 ----------------
__global__ void transpose_kernel(const float* __restrict__ wgp,
                                 const float* __restrict__ wup,
                                 const float* __restrict__ wdp,
                                 bf16* __restrict__ WgT,
                                 bf16* __restrict__ WuT,
                                 bf16* __restrict__ WdT) {
    __shared__ float tile[64 * 64];
    int m = blockIdx.y;
    int kind = m >> 3, e = m & 7;
    const float* src; bf16* dst; int R, C;
    if (kind == 0)      { src = wgp + (size_t)e * DDIM * HDIM; dst = WgT + (size_t)e * HDIM * DDIM; R = DDIM; C = HDIM; }
    else if (kind == 1) { src = wup + (size_t)e * DDIM * HDIM; dst = WuT + (size_t)e * HDIM * DDIM; R = DDIM; C = HDIM; }
    else                { src = wdp + (size_t)e * HDIM * DDIM; dst = WdT + (size_t)e * DDIM * HDIM; R = HDIM; C = DDIM; }

    int nR = R >> 6;
    int t = blockIdx.x;
    int tr = t % nR, tc = t / nR;
    int r0 = tr << 6, c0 = tc << 6;
    int tid = threadIdx.x;

#pragma unroll
    for (int i = 0; i < 4; ++i) {
        int idx = i * 256 + tid;
        int rr = idx >> 4, c4 = idx & 15;
        int cs = c4 ^ ((rr >> 3) & 3);
        float4 v = *(const float4*)(src + (size_t)(r0 + rr) * C + c0 + c4 * 4);
        *(float4*)&tile[rr * 64 + cs * 4] = v;
    }
    __syncthreads();

#pragma unroll
    for (int i = 0; i < 2; ++i) {
        int idx = i * 256 + tid;
        int cc = idx >> 3, rp0 = (idx & 7) * 8;
        bf16x8 o;
#pragma unroll
        for (int j = 0; j < 8; ++j) {
            int r = rp0 + j;
            o[j] = (bf16)tile[r * 64 + (((cc >> 2) ^ ((r >> 3) & 3)) << 2) + (cc & 3)];
        }
        *(bf16x8*)(dst + (size_t)(c0 + cc) * R + r0 + rp0) = o;
    }
}

// ---------------- GEMM1: G = silu(Xg@Wg) * (Xg@Wu) ----------------
// 128 rows x (64 gate + 64 up) cols, BK=64, dbuf, counted vmcnt, 2 barriers/K-tile.
__launch_bounds__(256)
__global__ void gemm1_kernel(const bf16* __restrict__ Xg,
                             const bf16* __restrict__ WgT,
                             const bf16* __restrict__ WuT,
                             const int* __restrict__ ctrl,
                             bf16* __restrict__ G) {
    extern __shared__ __align__(16) bf16 smem[];   // 32768 elems: A[2][8192] | B[2][8192]

    int bid = blockIdx.x;
    int id = (bid & 7) * (NMT * NT1 / 8) + (bid >> 3);   // XCD swizzle; 3024 % 8 == 0
    int gm = id / NT1, nt = id % NT1;
    const int* offs = ctrl + 16;
    int row0 = gm * 128;
    if (row0 >= offs[NEXP]) return;
    int e = 0;
#pragma unroll
    for (int i = 1; i < NEXP; ++i) if (row0 >= offs[i]) e = i;
    int n0 = nt * 64;

    int tid = threadIdx.x;
    int wv = tid >> 6, lane = tid & 63;
    int wm = wv & 1, wn = wv >> 1;
    int quad = lane >> 4, lm = lane & 15;

    const bf16* srcA[4];
    const bf16* srcB[4];
#pragma unroll
    for (int j = 0; j < 4; ++j) {
        int c = j * 256 + tid;
        int r = c >> 3, q = c & 7;
        srcA[j] = Xg + (size_t)(row0 + r) * DDIM + (q ^ (r & 7)) * 8;
        const bf16* wb = (j < 2) ? (WgT + ((size_t)e * HDIM + n0 + r) * DDIM)
                                 : (WuT + ((size_t)e * HDIM + n0 + (r - 64)) * DDIM);
        srcB[j] = wb + (q ^ (r & 7)) * 8;
    }

#define STG_A1(KT, BUF) do { int ko_ = (KT) * 64; \
    _Pragma("unroll") for (int j_ = 0; j_ < 4; ++j_) \
        async_copy16(srcA[j_] + ko_, smem + (BUF) * 8192 + (j_ * 256 + tid) * 8); } while (0)
#define STG_B1(KT, BUF) do { int ko_ = (KT) * 64; \
    _Pragma("unroll") for (int j_ = 0; j_ < 4; ++j_) \
        async_copy16(srcB[j_] + ko_, smem + 16384 + (BUF) * 8192 + (j_ * 256 + tid) * 8); } while (0)

    int aOff = (wm * 64 + lm) * 64;
    int bOff = (wn * 32 + lm) * 64;
    int cA = (quad ^ (lm & 7)) * 8;

    f32x4 accg[4][2], accu[4][2];
#pragma unroll
    for (int mi = 0; mi < 4; ++mi)
#pragma unroll
        for (int nf = 0; nf < 2; ++nf) { accg[mi][nf] = 0.f; accu[mi][nf] = 0.f; }

    STG_A1(0, 0);
    STG_B1(0, 0);

#pragma unroll
    for (int kt = 0; kt < NK1; ++kt) {
        const int buf = kt & 1;
        const bf16* pa = smem + buf * 8192;
        const bf16* pb = smem + 16384 + buf * 8192;
        if (kt + 1 < NK1) { STG_A1(kt + 1, buf ^ 1); VMC4; }
        else              { VMC0; }
        BAR;

        bf16x8 af[4][2], bbg[2][2], bbu[2][2];
#pragma unroll
        for (int mi = 0; mi < 4; ++mi)
#pragma unroll
            for (int ks = 0; ks < 2; ++ks)
                af[mi][ks] = *(const bf16x8*)(pa + aOff + mi * 1024 + (cA ^ (ks * 32)));
#pragma unroll
        for (int nf = 0; nf < 2; ++nf)
#pragma unroll
            for (int ks = 0; ks < 2; ++ks)
                bbg[nf][ks] = *(const bf16x8*)(pb + bOff + nf * 1024 + (cA ^ (ks * 32)));
        LGKM0;
        __builtin_amdgcn_s_setprio(1);
#pragma unroll
        for (int mi = 0; mi < 4; ++mi)
#pragma unroll
            for (int nf = 0; nf < 2; ++nf)
#pragma unroll
                for (int ks = 0; ks < 2; ++ks)
                    accg[mi][nf] = __builtin_amdgcn_mfma_f32_16x16x32_bf16(af[mi][ks], bbg[nf][ks], accg[mi][nf], 0, 0, 0);
        __builtin_amdgcn_s_setprio(0);

        if (kt + 1 < NK1) STG_B1(kt + 1, buf ^ 1);

#pragma unroll
        for (int nf = 0; nf < 2; ++nf)
#pragma unroll
            for (int ks = 0; ks < 2; ++ks)
                bbu[nf][ks] = *(const bf16x8*)(pb + 4096 + bOff + nf * 1024 + (cA ^ (ks * 32)));
        LGKM0;
        __builtin_amdgcn_s_setprio(1);
#pragma unroll
        for (int mi = 0; mi < 4; ++mi)
#pragma unroll
            for (int nf = 0; nf < 2; ++nf)
#pragma unroll
                for (int ks = 0; ks < 2; ++ks)
                    accu[mi][nf] = __builtin_amdgcn_mfma_f32_16x16x32_bf16(af[mi][ks], bbu[nf][ks], accu[mi][nf], 0, 0, 0);
        __builtin_amdgcn_s_setprio(0);
        BAR;
    }

    // epilogue: SwiGLU + LDS repack -> coalesced bf16x8 stores
#pragma unroll
    for (int mi = 0; mi < 4; ++mi)
#pragma unroll
        for (int nj = 0; nj < 2; ++nj)
#pragma unroll
            for (int r = 0; r < 4; ++r) {
                float gg = accg[mi][nj][r];
                float u = accu[mi][nj][r];
                float val = (gg / (1.f + __expf(-gg))) * u;
                int rl = wm * 64 + mi * 16 + quad * 4 + r;
                int c  = wn * 32 + nj * 16 + lm;
                smem[rl * 72 + c] = (bf16)val;
            }
    __syncthreads();
#pragma unroll
    for (int i = 0; i < 4; ++i) {
        int idx = (i * 256 + tid) * 8;
        int row = idx >> 6, c = idx & 63;
        bf16x8 v = *(const bf16x8*)(smem + row * 72 + c);
        *(bf16x8*)(G + (size_t)(row0 + row) * HDIM + n0 + c) = v;
    }
#undef STG_A1
#undef STG_B1
}

// ---------------- GEMM2: Y_s = G[:, s*1344:(s+1)*1344] @ Wd[s half] ----------------
__launch_bounds__(256)
__global__ void gemm2_kernel(const bf16* __restrict__ G,
                             const bf16* __restrict__ WdT,
                             const int* __restrict__ ctrl,
                             bf16* __restrict__ Ya,
                             bf16* __restrict__ Yb) {
    extern __shared__ __align__(16) bf16 smem[];   // 32768 elems: A[2][8192] | B[2][8192]

    int bid = blockIdx.x;
    int id = (bid & 7) * (NMT * NT2 * 2 / 8) + (bid >> 3);   // 864 % 8 == 0
    int gm = id / (NT2 * 2);
    int r2 = id % (NT2 * 2);
    int nt = r2 >> 1, s = r2 & 1;
    const int* offs = ctrl + 16;
    int row0 = gm * 128;
    if (row0 >= offs[NEXP]) return;
    int e = 0;
#pragma unroll
    for (int i = 1; i < NEXP; ++i) if (row0 >= offs[i]) e = i;
    int n0 = nt * 128;

    int tid = threadIdx.x;
    int wv = tid >> 6, lane = tid & 63;
    int wm = wv & 1, wn = wv >> 1;
    int quad = lane >> 4, lm = lane & 15;

    const bf16* srcA[4];
    const bf16* srcB[4];
#pragma unroll
    for (int j = 0; j < 4; ++j) {
        int c = j * 256 + tid;
        int r = c >> 3, q = c & 7;
        srcA[j] = G + (size_t)(row0 + r) * HDIM + s * KHALF + (q ^ (r & 7)) * 8;
        srcB[j] = WdT + ((size_t)e * DDIM + n0 + r) * HDIM + s * KHALF + (q ^ (r & 7)) * 8;
    }

#define STG_A2(KT, BUF) do { int ko_ = (KT) * 64; \
    _Pragma("unroll") for (int j_ = 0; j_ < 4; ++j_) \
        async_copy16(srcA[j_] + ko_, smem + (BUF) * 8192 + (j_ * 256 + tid) * 8); } while (0)
#define STG_B2(KT, BUF) do { int ko_ = (KT) * 64; \
    _Pragma("unroll") for (int j_ = 0; j_ < 4; ++j_) \
        async_copy16(srcB[j_] + ko_, smem + 16384 + (BUF) * 8192 + (j_ * 256 + tid) * 8); } while (0)

    int aOff = (wm * 64 + lm) * 64;
    int bOff = (wn * 64 + lm) * 64;
    int cA = (quad ^ (lm & 7)) * 8;

    f32x4 acc[4][4];
#pragma unroll
    for (int mi = 0; mi < 4; ++mi)
#pragma unroll
        for (int nf = 0; nf < 4; ++nf) acc[mi][nf] = 0.f;

    STG_A2(0, 0);
    STG_B2(0, 0);

#pragma unroll
    for (int kt = 0; kt < NK2; ++kt) {
        const int buf = kt & 1;
        const bf16* pa = smem + buf * 8192;
        const bf16* pb = smem + 16384 + buf * 8192;
        if (kt + 1 < NK2) { STG_A2(kt + 1, buf ^ 1); VMC4; }
        else              { VMC0; }
        BAR;

        bf16x8 af[4][2], bb[4][2];
#pragma unroll
        for (int mi = 0; mi < 4; ++mi)
#pragma unroll
            for (int ks = 0; ks < 2; ++ks)
                af[mi][ks] = *(const bf16x8*)(pa + aOff + mi * 1024 + (cA ^ (ks * 32)));
#pragma unroll
        for (int nf = 0; nf < 2; ++nf)
#pragma unroll
            for (int ks = 0; ks < 2; ++ks)
                bb[nf][ks] = *(const bf16x8*)(pb + bOff + nf * 1024 + (cA ^ (ks * 32)));
        LGKM0;
        __builtin_amdgcn_s_setprio(1);
#pragma unroll
        for (int mi = 0; mi < 4; ++mi)
#pragma unroll
            for (int nf = 0; nf < 2; ++nf)
#pragma unroll
                for (int ks = 0; ks < 2; ++ks)
                    acc[mi][nf] = __builtin_amdgcn_mfma_f32_16x16x32_bf16(af[mi][ks], bb[nf][ks], acc[mi][nf], 0, 0, 0);
        __builtin_amdgcn_s_setprio(0);

        if (kt + 1 < NK2) STG_B2(kt + 1, buf ^ 1);

#pragma unroll
        for (int nf = 2; nf < 4; ++nf)
#pragma unroll
            for (int ks = 0; ks < 2; ++ks)
                bb[nf][ks] = *(const bf16x8*)(pb + bOff + nf * 1024 + (cA ^ (ks * 32)));
        LGKM0;
        __builtin_amdgcn_s_setprio(1);
#pragma unroll
        for (int mi = 0; mi < 4; ++mi)
#pragma unroll
            for (int nf = 2; nf < 4; ++nf)
#pragma unroll
                for (int ks = 0; ks < 2; ++ks)
                    acc[mi][nf] = __builtin_amdgcn_mfma_f32_16x16x32_bf16(af[mi][ks], bb[nf][ks], acc[mi][nf], 0, 0, 0);
        __builtin_amdgcn_s_setprio(0);
        BAR;
    }

    bf16* Y = s ? Yb : Ya;
#pragma unroll
    for (int rr = 0; rr < 2; ++rr) {
#pragma unroll
        for (int mi = 0; mi < 4; ++mi)
#pragma unroll
            for (int nj = 0; nj < 2; ++nj) {
                int ni = rr * 2 + nj;
#pragma unroll
                for (int r = 0; r < 4; ++r) {
                    int rl = wm * 64 + mi * 16 + quad * 4 + r;
                    int c  = wn * 32 + nj * 16 + lm;
                    smem[rl * 72 + c] = (bf16)acc[mi][ni][r];
                }
            }
        __syncthreads();
#pragma unroll
        for (int i = 0; i < 4; ++i) {
            int idx = (i * 256 + tid) * 8;
            int row = idx >> 6, c = idx & 63;
            bf16x8 v = *(const bf16x8*)(smem + row * 72 + c);
            int col = n0 + ((c >> 5) << 6) + (c & 31) + rr * 32;
            *(bf16x8*)(Y + (size_t)(row0 + row) * DDIM + col) = v;
        }
        if (rr == 0) __syncthreads();
    }
#undef STG_A2
#undef STG_B2
}

// ---------------- Combine ----------------
__global__ void combine_kernel(const bf16* __restrict__ Ya,
                               const bf16* __restrict__ Yb,
                               const int* __restrict__ tok_pos,
                               const float* __restrict__ tok_w,
                               float* __restrict__ out) {
    int t = blockIdx.x;
    int i = threadIdx.x;           // 192 threads x 4 cols
    int p0 = tok_pos[t * 2 + 0], p1 = tok_pos[t * 2 + 1];
    float w0 = tok_w[t * 2 + 0], w1 = tok_w[t * 2 + 1];
    bf16x4 a0 = *(const bf16x4*)(Ya + (size_t)p0 * DDIM + i * 4);
    bf16x4 b0 = *(const bf16x4*)(Yb + (size_t)p0 * DDIM + i * 4);
    bf16x4 a1 = *(const bf16x4*)(Ya + (size_t)p1 * DDIM + i * 4);
    bf16x4 b1 = *(const bf16x4*)(Yb + (size_t)p1 * DDIM + i * 4);
    float4 o;
    o.x = w0 * ((float)a0.x + (float)b0.x) + w1 * ((float)a1.x + (float)b1.x);
    o.y = w0 * ((float)a0.y + (float)b0.y) + w1 * ((float)a1.y + (float)b1.y);
    o.z = w0 * ((float)a0.z + (float)b0.z) + w1 * ((float)a1.z + (float)b1.z);
    o.w = w0 * ((float)a0.w + (float)b0.w) + w1 * ((float)a1.w + (float)b1.w);
    *(float4*)(out + (size_t)t * DDIM + i * 4) = o;
}

extern "C" void kernel_launch(void* const* d_in, const int* in_sizes, int n_in,
                              void* d_out, int out_size, void* d_ws, size_t ws_size,
                              hipStream_t stream) {
    const float* x      = (const float*)d_in[0];
    const float* gate_w = (const float*)d_in[1];
    const float* ebias  = (const float*)d_in[2];
    const float* wgp    = (const float*)d_in[3];
    const float* wup    = (const float*)d_in[4];
    const float* wdp    = (const float*)d_in[5];
    float* out = (float*)d_out;

    int*   ctrl     = (int*)d_ws;                          // 128 ints
    int*   tok_e    = ctrl + 128;                          // 2T
    float* tok_w    = (float*)(tok_e + 2 * T_TOK);         // 2T
    int*   pair_tok = (int*)(tok_w + 2 * T_TOK);           // RMAX
    int*   tok_pos  = pair_tok + RMAX;                     // 2T
    int*   cpart    = tok_pos + 2 * T_TOK;                 // RBLK*8 ints
    float* zpart    = (float*)(cpart + RBLK * NEXP);       // RBLK floats
    bf16*  Xg       = (bf16*)(zpart + RBLK);               // RMAX*768 (reused as Ya)
    bf16*  Ya       = Xg;
    bf16*  Yb       = Xg + (size_t)RMAX * DDIM;            // RMAX*768
    bf16*  G        = Yb + (size_t)RMAX * DDIM;            // RMAX*2688
    bf16*  WgT      = G + (size_t)RMAX * HDIM;
    bf16*  WuT      = WgT + (size_t)NEXP * DDIM * HDIM;
    bf16*  WdT      = WuT + (size_t)NEXP * DDIM * HDIM;

    hipMemsetAsync(out + (size_t)T_TOK * DDIM, 0, sizeof(float), stream);  // z_loss
    hipMemsetAsync(d_ws, 0, 512, stream);                                  // ctrl

    router_kernel<<<RBLK, 256, 0, stream>>>(x, gate_w, ebias, tok_e, tok_w, cpart, zpart);
    setup_kernel<<<1, 1024, 0, stream>>>(ctrl, cpart, zpart, tok_e, pair_tok, tok_pos,
                                         out + (size_t)T_TOK * DDIM);
    transpose_kernel<<<dim3(504, 24), 256, 0, stream>>>(wgp, wup, wdp, WgT, WuT, WdT);
    gather_kernel<<<RMAX, 192, 0, stream>>>(x, ctrl, pair_tok, Xg);
    gemm1_kernel<<<NMT * NT1, 256, 65536, stream>>>(Xg, WgT, WuT, ctrl, G);
    gemm2_kernel<<<NMT * NT2 * 2, 256, 65536, stream>>>(G, WdT, ctrl, Ya, Yb);
    combine_kernel<<<T_TOK, 192, 0, stream>>>(Ya, Yb, tok_pos, tok_w, out);
}

// Round 5
// 371.838 us; speedup vs baseline: 1.5046x; 1.0328x over previous
//
#include <hip/hip_runtime.h>
#include <hip/hip_bf16.h>
#include <math.h>

typedef __bf16 bf16;
typedef bf16 bf16x2 __attribute__((ext_vector_type(2)));
typedef bf16 bf16x4 __attribute__((ext_vector_type(4)));
typedef bf16 bf16x8 __attribute__((ext_vector_type(8)));
typedef float f32x4 __attribute__((ext_vector_type(4)));

#define T_TOK 4096
#define DDIM  768
#define HDIM  2688
#define NEXP  8
#define RMAX  9216            // max padded pair rows (8192 + 8*127 rounded up)
#define NMT   (RMAX / 128)    // 72 mtiles
#define NT1   (HDIM / 64)     // 42 n-tiles gemm1
#define NT2   (DDIM / 128)    // 6 n-tiles gemm2
#define KHALF (HDIM / 2)      // 1344
#define NK1   (DDIM / 64)     // 12 K-tiles gemm1
#define NK2   (KHALF / 64)    // 21 K-tiles gemm2
#define RBLK  (T_TOK / 4)     // 1024 router blocks
#define TBLK  12096           // transpose blocks (24 matrices x 504 tiles)

__device__ __forceinline__ void async_copy16(const void* g, void* l) {
    __builtin_amdgcn_global_load_lds(
        (__attribute__((address_space(1))) void*)g,
        (__attribute__((address_space(3))) void*)l,
        16, 0, 0);
}

#define LGKM0 do { asm volatile("s_waitcnt lgkmcnt(0)" ::: "memory"); __builtin_amdgcn_sched_barrier(0); } while(0)
#define VMC8  asm volatile("s_waitcnt vmcnt(8)" ::: "memory")
#define VMC0  asm volatile("s_waitcnt vmcnt(0)" ::: "memory")
#define BAR   __builtin_amdgcn_s_barrier()

// ---------------- Prep: fused weight-transpose + router (independent work, one dispatch) ----
// blocks [0, TBLK): fp32->bf16 weight transpose.  [TBLK, TBLK+RBLK): router (no global atomics).
__global__ void prep_kernel(const float* __restrict__ wgp,
                            const float* __restrict__ wup,
                            const float* __restrict__ wdp,
                            bf16* __restrict__ WgT,
                            bf16* __restrict__ WuT,
                            bf16* __restrict__ WdT,
                            const float* __restrict__ x,
                            const float* __restrict__ gate_w,
                            const float* __restrict__ ebias,
                            int* __restrict__ tok_e,
                            float* __restrict__ tok_w,
                            int* __restrict__ cpart,
                            float* __restrict__ zpart) {
    __shared__ __align__(16) float shbuf[NEXP * DDIM];   // 24 KiB (transpose uses first 16 KiB)
    __shared__ int hist[NEXP];
    __shared__ float z4[4];
    int b = blockIdx.x;
    int tid = threadIdx.x;

    if (b < TBLK) {
        // ---- transpose: 64x64 fp32 tile, XOR-swizzled LDS, bf16x8 stores ----
        float* tile = shbuf;
        int m = b / 504, t = b % 504;
        int kind = m >> 3, e = m & 7;
        const float* src; bf16* dst; int R, C;
        if (kind == 0)      { src = wgp + (size_t)e * DDIM * HDIM; dst = WgT + (size_t)e * HDIM * DDIM; R = DDIM; C = HDIM; }
        else if (kind == 1) { src = wup + (size_t)e * DDIM * HDIM; dst = WuT + (size_t)e * HDIM * DDIM; R = DDIM; C = HDIM; }
        else                { src = wdp + (size_t)e * HDIM * DDIM; dst = WdT + (size_t)e * DDIM * HDIM; R = HDIM; C = DDIM; }

        int nR = R >> 6;
        int tr = t % nR, tc = t / nR;
        int r0 = tr << 6, c0 = tc << 6;

#pragma unroll
        for (int i = 0; i < 4; ++i) {
            int idx = i * 256 + tid;
            int rr = idx >> 4, c4 = idx & 15;
            int cs = c4 ^ ((rr >> 3) & 3);
            float4 v = *(const float4*)(src + (size_t)(r0 + rr) * C + c0 + c4 * 4);
            *(float4*)&tile[rr * 64 + cs * 4] = v;
        }
        __syncthreads();

#pragma unroll
        for (int i = 0; i < 2; ++i) {
            int idx = i * 256 + tid;
            int cc = idx >> 3, rp0 = (idx & 7) * 8;
            bf16x8 o;
#pragma unroll
            for (int j = 0; j < 8; ++j) {
                int r = rp0 + j;
                o[j] = (bf16)tile[r * 64 + (((cc >> 2) ^ ((r >> 3) & 3)) << 2) + (cc & 3)];
            }
            *(bf16x8*)(dst + (size_t)(c0 + cc) * R + r0 + rp0) = o;
        }
        return;
    }

    // ---- router ----
    int rb = b - TBLK;
    float* gw = shbuf;
    if (tid < NEXP) hist[tid] = 0;
    for (int i = tid; i < NEXP * DDIM / 4; i += 256)
        ((float4*)gw)[i] = ((const float4*)gate_w)[i];
    __syncthreads();

    int wv = tid >> 6, lane = tid & 63;
    int t = rb * 4 + wv;
    const float* xr = x + (size_t)t * DDIM;

    float4 xv[3];
#pragma unroll
    for (int j = 0; j < 3; ++j) xv[j] = ((const float4*)xr)[j * 64 + lane];

    float acc[NEXP];
#pragma unroll
    for (int e = 0; e < NEXP; ++e) {
        float a = 0.f;
#pragma unroll
        for (int j = 0; j < 3; ++j) {
            float4 w = ((const float4*)(gw + e * DDIM))[j * 64 + lane];
            a += xv[j].x * w.x + xv[j].y * w.y + xv[j].z * w.z + xv[j].w * w.w;
        }
        acc[e] = a;
    }
#pragma unroll
    for (int e = 0; e < NEXP; ++e) {
#pragma unroll
        for (int off = 32; off > 0; off >>= 1) acc[e] += __shfl_xor(acc[e], off);
    }

    if (lane == 0) {
        float bb[NEXP];
#pragma unroll
        for (int e = 0; e < NEXP; ++e) bb[e] = acc[e] + ebias[e];
        int i0 = 0;
#pragma unroll
        for (int e = 1; e < NEXP; ++e) if (bb[e] > bb[i0]) i0 = e;
        int i1 = (i0 == 0) ? 1 : 0;
        float b1 = bb[i1];
#pragma unroll
        for (int e = 0; e < NEXP; ++e) if (e != i0 && bb[e] > b1) { b1 = bb[e]; i1 = e; }

        float l0 = acc[i0], l1 = acc[i1];
        float mx = fmaxf(l0, l1);
        float e0 = __expf(l0 - mx), e1 = __expf(l1 - mx);
        float inv = 1.f / (e0 + e1);
        tok_e[t * 2 + 0] = i0;
        tok_e[t * 2 + 1] = i1;
        tok_w[t * 2 + 0] = e0 * inv;
        tok_w[t * 2 + 1] = e1 * inv;
        atomicAdd(&hist[i0], 1);   // LDS atomic
        atomicAdd(&hist[i1], 1);

        float m8 = acc[0];
#pragma unroll
        for (int e = 1; e < NEXP; ++e) m8 = fmaxf(m8, acc[e]);
        float s = 0.f;
#pragma unroll
        for (int e = 0; e < NEXP; ++e) s += __expf(acc[e] - m8);
        float lse = m8 + __logf(s);
        z4[wv] = lse * lse;
    }
    __syncthreads();
    if (tid < NEXP) cpart[rb * NEXP + tid] = hist[tid];
    if (tid == NEXP) zpart[rb] = z4[0] + z4[1] + z4[2] + z4[3];
}

// ---------------- Setup: reduce partials -> counts/offsets/zloss, then scatter via LDS counters ----
__global__ void setup_kernel(int* __restrict__ ctrl,
                             const int* __restrict__ cpart,
                             const float* __restrict__ zpart,
                             const int* __restrict__ tok_e,
                             int* __restrict__ pair_tok,
                             int* __restrict__ tok_pos,
                             float* __restrict__ zloss) {
    __shared__ int whist[16][NEXP];
    __shared__ float wz[16];
    __shared__ int scnt[NEXP];
    int tid = threadIdx.x;              // 1024 threads = 16 waves
    int wv = tid >> 6, lane = tid & 63;

    int h[NEXP];
#pragma unroll
    for (int e = 0; e < NEXP; ++e) h[e] = cpart[tid * NEXP + e];
    float z = zpart[tid];
#pragma unroll
    for (int off = 32; off > 0; off >>= 1) {
#pragma unroll
        for (int e = 0; e < NEXP; ++e) h[e] += __shfl_xor(h[e], off);
        z += __shfl_xor(z, off);
    }
    if (lane == 0) {
#pragma unroll
        for (int e = 0; e < NEXP; ++e) whist[wv][e] = h[e];
        wz[wv] = z;
    }
    __syncthreads();
    if (tid == 0) {
        float zs = 0.f;
        for (int w = 0; w < 16; ++w) zs += wz[w];
        *zloss = (1e-5f / (float)T_TOK) * zs;
        int off = 0;
        for (int e = 0; e < NEXP; ++e) {
            int c = 0;
            for (int w = 0; w < 16; ++w) c += whist[w][e];
            ctrl[e] = c;
            ctrl[16 + e] = off;
            scnt[e] = off;
            off += (c + 127) & ~127;
        }
        ctrl[16 + NEXP] = off;
    }
    __syncthreads();
    for (int t = tid; t < T_TOK; t += 1024) {
#pragma unroll
        for (int k = 0; k < 2; ++k) {
            int e = tok_e[t * 2 + k];
            int pos = atomicAdd(&scnt[e], 1);   // LDS atomic
            pair_tok[pos] = t;
            tok_pos[t * 2 + k] = pos;
        }
    }
}

__global__ void gather_kernel(const float* __restrict__ x,
                              const int* __restrict__ ctrl,
                              const int* __restrict__ pair_tok,
                              bf16* __restrict__ Xg) {
    int r = blockIdx.x;
    int tid = threadIdx.x;  // 192 threads, 4 floats each
    const int* offs = ctrl + 16;
    int total = offs[8];
    int tok = -1;
    if (r < total) {
        int e = 0;
#pragma unroll
        for (int i = 1; i < NEXP; ++i) if (r >= offs[i]) e = i;
        if (r - offs[e] < ctrl[e]) tok = pair_tok[r];
    }
    bf16x4 o;
    if (tok >= 0) {
        float4 v = *(const float4*)(x + (size_t)tok * DDIM + tid * 4);
        o.x = (bf16)v.x; o.y = (bf16)v.y; o.z = (bf16)v.z; o.w = (bf16)v.w;
    } else {
        o.x = (bf16)0.f; o.y = (bf16)0.f; o.z = (bf16)0.f; o.w = (bf16)0.f;
    }
    *(bf16x4*)(Xg + (size_t)r * DDIM + tid * 4) = o;
}

// ---------------- GEMM1: G = silu(Xg@Wg) * (Xg@Wu) ----------------
// 128 rows x (64 gate + 64 up) cols, BK=64, dbuf. Full-tile-deep prefetch:
// A(kt+1)+B(kt+1) issued together at tile top; vmcnt(8) waits only tile-kt's loads
// (issued one full tile earlier -> latency covered by a whole tile of compute).
__launch_bounds__(256)
__global__ void gemm1_kernel(const bf16* __restrict__ Xg,
                             const bf16* __restrict__ WgT,
                             const bf16* __restrict__ WuT,
                             const int* __restrict__ ctrl,
                             bf16* __restrict__ G) {
    extern __shared__ __align__(16) bf16 smem[];   // 32768 elems: A[2][8192] | B[2][8192]

    int bid = blockIdx.x;
    int id = (bid & 7) * (NMT * NT1 / 8) + (bid >> 3);   // XCD swizzle; 3024 % 8 == 0
    int gm = id / NT1, nt = id % NT1;
    const int* offs = ctrl + 16;
    int row0 = gm * 128;
    if (row0 >= offs[NEXP]) return;
    int e = 0;
#pragma unroll
    for (int i = 1; i < NEXP; ++i) if (row0 >= offs[i]) e = i;
    int n0 = nt * 64;

    int tid = threadIdx.x;
    int wv = tid >> 6, lane = tid & 63;
    int wm = wv & 1, wn = wv >> 1;
    int quad = lane >> 4, lm = lane & 15;

    const bf16* srcA[4];
    const bf16* srcB[4];
#pragma unroll
    for (int j = 0; j < 4; ++j) {
        int c = j * 256 + tid;
        int r = c >> 3, q = c & 7;
        srcA[j] = Xg + (size_t)(row0 + r) * DDIM + (q ^ (r & 7)) * 8;
        const bf16* wb = (j < 2) ? (WgT + ((size_t)e * HDIM + n0 + r) * DDIM)
                                 : (WuT + ((size_t)e * HDIM + n0 + (r - 64)) * DDIM);
        srcB[j] = wb + (q ^ (r & 7)) * 8;
    }

#define STG_A1(KT, BUF) do { int ko_ = (KT) * 64; \
    _Pragma("unroll") for (int j_ = 0; j_ < 4; ++j_) \
        async_copy16(srcA[j_] + ko_, smem + (BUF) * 8192 + (j_ * 256 + tid) * 8); } while (0)
#define STG_B1(KT, BUF) do { int ko_ = (KT) * 64; \
    _Pragma("unroll") for (int j_ = 0; j_ < 4; ++j_) \
        async_copy16(srcB[j_] + ko_, smem + 16384 + (BUF) * 8192 + (j_ * 256 + tid) * 8); } while (0)

    int aOff = (wm * 64 + lm) * 64;
    int bOff = (wn * 32 + lm) * 64;
    int cA = (quad ^ (lm & 7)) * 8;

    f32x4 accg[4][2], accu[4][2];
#pragma unroll
    for (int mi = 0; mi < 4; ++mi)
#pragma unroll
        for (int nf = 0; nf < 2; ++nf) { accg[mi][nf] = 0.f; accu[mi][nf] = 0.f; }

    STG_A1(0, 0);
    STG_B1(0, 0);

#pragma unroll
    for (int kt = 0; kt < NK1; ++kt) {
        const int buf = kt & 1;
        const bf16* pa = smem + buf * 8192;
        const bf16* pb = smem + 16384 + buf * 8192;
        if (kt + 1 < NK1) { STG_A1(kt + 1, buf ^ 1); STG_B1(kt + 1, buf ^ 1); VMC8; }
        else              { VMC0; }
        BAR;

        bf16x8 af[4][2], bbg[2][2], bbu[2][2];
#pragma unroll
        for (int mi = 0; mi < 4; ++mi)
#pragma unroll
            for (int ks = 0; ks < 2; ++ks)
                af[mi][ks] = *(const bf16x8*)(pa + aOff + mi * 1024 + (cA ^ (ks * 32)));
#pragma unroll
        for (int nf = 0; nf < 2; ++nf)
#pragma unroll
            for (int ks = 0; ks < 2; ++ks)
                bbg[nf][ks] = *(const bf16x8*)(pb + bOff + nf * 1024 + (cA ^ (ks * 32)));
        LGKM0;
        __builtin_amdgcn_s_setprio(1);
#pragma unroll
        for (int mi = 0; mi < 4; ++mi)
#pragma unroll
            for (int nf = 0; nf < 2; ++nf)
#pragma unroll
                for (int ks = 0; ks < 2; ++ks)
                    accg[mi][nf] = __builtin_amdgcn_mfma_f32_16x16x32_bf16(af[mi][ks], bbg[nf][ks], accg[mi][nf], 0, 0, 0);
        __builtin_amdgcn_s_setprio(0);

#pragma unroll
        for (int nf = 0; nf < 2; ++nf)
#pragma unroll
            for (int ks = 0; ks < 2; ++ks)
                bbu[nf][ks] = *(const bf16x8*)(pb + 4096 + bOff + nf * 1024 + (cA ^ (ks * 32)));
        LGKM0;
        __builtin_amdgcn_s_setprio(1);
#pragma unroll
        for (int mi = 0; mi < 4; ++mi)
#pragma unroll
            for (int nf = 0; nf < 2; ++nf)
#pragma unroll
                for (int ks = 0; ks < 2; ++ks)
                    accu[mi][nf] = __builtin_amdgcn_mfma_f32_16x16x32_bf16(af[mi][ks], bbu[nf][ks], accu[mi][nf], 0, 0, 0);
        __builtin_amdgcn_s_setprio(0);
        BAR;
    }

    // epilogue: SwiGLU + LDS repack -> coalesced bf16x8 stores
#pragma unroll
    for (int mi = 0; mi < 4; ++mi)
#pragma unroll
        for (int nj = 0; nj < 2; ++nj)
#pragma unroll
            for (int r = 0; r < 4; ++r) {
                float gg = accg[mi][nj][r];
                float u = accu[mi][nj][r];
                float val = (gg / (1.f + __expf(-gg))) * u;
                int rl = wm * 64 + mi * 16 + quad * 4 + r;
                int c  = wn * 32 + nj * 16 + lm;
                smem[rl * 72 + c] = (bf16)val;
            }
    __syncthreads();
#pragma unroll
    for (int i = 0; i < 4; ++i) {
        int idx = (i * 256 + tid) * 8;
        int row = idx >> 6, c = idx & 63;
        bf16x8 v = *(const bf16x8*)(smem + row * 72 + c);
        *(bf16x8*)(G + (size_t)(row0 + row) * HDIM + n0 + c) = v;
    }
#undef STG_A1
#undef STG_B1
}

// ---------------- GEMM2: Y_s = G[:, s*1344:(s+1)*1344] @ Wd[s half] ----------------
__launch_bounds__(256)
__global__ void gemm2_kernel(const bf16* __restrict__ G,
                             const bf16* __restrict__ WdT,
                             const int* __restrict__ ctrl,
                             bf16* __restrict__ Ya,
                             bf16* __restrict__ Yb) {
    extern __shared__ __align__(16) bf16 smem[];   // 32768 elems: A[2][8192] | B[2][8192]

    int bid = blockIdx.x;
    int id = (bid & 7) * (NMT * NT2 * 2 / 8) + (bid >> 3);   // 864 % 8 == 0
    int gm = id / (NT2 * 2);
    int r2 = id % (NT2 * 2);
    int nt = r2 >> 1, s = r2 & 1;
    const int* offs = ctrl + 16;
    int row0 = gm * 128;
    if (row0 >= offs[NEXP]) return;
    int e = 0;
#pragma unroll
    for (int i = 1; i < NEXP; ++i) if (row0 >= offs[i]) e = i;
    int n0 = nt * 128;

    int tid = threadIdx.x;
    int wv = tid >> 6, lane = tid & 63;
    int wm = wv & 1, wn = wv >> 1;
    int quad = lane >> 4, lm = lane & 15;

    const bf16* srcA[4];
    const bf16* srcB[4];
#pragma unroll
    for (int j = 0; j < 4; ++j) {
        int c = j * 256 + tid;
        int r = c >> 3, q = c & 7;
        srcA[j] = G + (size_t)(row0 + r) * HDIM + s * KHALF + (q ^ (r & 7)) * 8;
        srcB[j] = WdT + ((size_t)e * DDIM + n0 + r) * HDIM + s * KHALF + (q ^ (r & 7)) * 8;
    }

#define STG_A2(KT, BUF) do { int ko_ = (KT) * 64; \
    _Pragma("unroll") for (int j_ = 0; j_ < 4; ++j_) \
        async_copy16(srcA[j_] + ko_, smem + (BUF) * 8192 + (j_ * 256 + tid) * 8); } while (0)
#define STG_B2(KT, BUF) do { int ko_ = (KT) * 64; \
    _Pragma("unroll") for (int j_ = 0; j_ < 4; ++j_) \
        async_copy16(srcB[j_] + ko_, smem + 16384 + (BUF) * 8192 + (j_ * 256 + tid) * 8); } while (0)

    int aOff = (wm * 64 + lm) * 64;
    int bOff = (wn * 64 + lm) * 64;
    int cA = (quad ^ (lm & 7)) * 8;

    f32x4 acc[4][4];
#pragma unroll
    for (int mi = 0; mi < 4; ++mi)
#pragma unroll
        for (int nf = 0; nf < 4; ++nf) acc[mi][nf] = 0.f;

    STG_A2(0, 0);
    STG_B2(0, 0);

#pragma unroll
    for (int kt = 0; kt < NK2; ++kt) {
        const int buf = kt & 1;
        const bf16* pa = smem + buf * 8192;
        const bf16* pb = smem + 16384 + buf * 8192;
        if (kt + 1 < NK2) { STG_A2(kt + 1, buf ^ 1); STG_B2(kt + 1, buf ^ 1); VMC8; }
        else              { VMC0; }
        BAR;

        bf16x8 af[4][2], bb[4][2];
#pragma unroll
        for (int mi = 0; mi < 4; ++mi)
#pragma unroll
            for (int ks = 0; ks < 2; ++ks)
                af[mi][ks] = *(const bf16x8*)(pa + aOff + mi * 1024 + (cA ^ (ks * 32)));
#pragma unroll
        for (int nf = 0; nf < 2; ++nf)
#pragma unroll
            for (int ks = 0; ks < 2; ++ks)
                bb[nf][ks] = *(const bf16x8*)(pb + bOff + nf * 1024 + (cA ^ (ks * 32)));
        LGKM0;
        __builtin_amdgcn_s_setprio(1);
#pragma unroll
        for (int mi = 0; mi < 4; ++mi)
#pragma unroll
            for (int nf = 0; nf < 2; ++nf)
#pragma unroll
                for (int ks = 0; ks < 2; ++ks)
                    acc[mi][nf] = __builtin_amdgcn_mfma_f32_16x16x32_bf16(af[mi][ks], bb[nf][ks], acc[mi][nf], 0, 0, 0);
        __builtin_amdgcn_s_setprio(0);

#pragma unroll
        for (int nf = 2; nf < 4; ++nf)
#pragma unroll
            for (int ks = 0; ks < 2; ++ks)
                bb[nf][ks] = *(const bf16x8*)(pb + bOff + nf * 1024 + (cA ^ (ks * 32)));
        LGKM0;
        __builtin_amdgcn_s_setprio(1);
#pragma unroll
        for (int mi = 0; mi < 4; ++mi)
#pragma unroll
            for (int nf = 2; nf < 4; ++nf)
#pragma unroll
                for (int ks = 0; ks < 2; ++ks)
                    acc[mi][nf] = __builtin_amdgcn_mfma_f32_16x16x32_bf16(af[mi][ks], bb[nf][ks], acc[mi][nf], 0, 0, 0);
        __builtin_amdgcn_s_setprio(0);
        BAR;
    }

    bf16* Y = s ? Yb : Ya;
#pragma unroll
    for (int rr = 0; rr < 2; ++rr) {
#pragma unroll
        for (int mi = 0; mi < 4; ++mi)
#pragma unroll
            for (int nj = 0; nj < 2; ++nj) {
                int ni = rr * 2 + nj;
#pragma unroll
                for (int r = 0; r < 4; ++r) {
                    int rl = wm * 64 + mi * 16 + quad * 4 + r;
                    int c  = wn * 32 + nj * 16 + lm;
                    smem[rl * 72 + c] = (bf16)acc[mi][ni][r];
                }
            }
        __syncthreads();
#pragma unroll
        for (int i = 0; i < 4; ++i) {
            int idx = (i * 256 + tid) * 8;
            int row = idx >> 6, c = idx & 63;
            bf16x8 v = *(const bf16x8*)(smem + row * 72 + c);
            int col = n0 + ((c >> 5) << 6) + (c & 31) + rr * 32;
            *(bf16x8*)(Y + (size_t)(row0 + row) * DDIM + col) = v;
        }
        if (rr == 0) __syncthreads();
    }
#undef STG_A2
#undef STG_B2
}

// ---------------- Combine ----------------
__global__ void combine_kernel(const bf16* __restrict__ Ya,
                               const bf16* __restrict__ Yb,
                               const int* __restrict__ tok_pos,
                               const float* __restrict__ tok_w,
                               float* __restrict__ out) {
    int t = blockIdx.x;
    int i = threadIdx.x;           // 192 threads x 4 cols
    int p0 = tok_pos[t * 2 + 0], p1 = tok_pos[t * 2 + 1];
    float w0 = tok_w[t * 2 + 0], w1 = tok_w[t * 2 + 1];
    bf16x4 a0 = *(const bf16x4*)(Ya + (size_t)p0 * DDIM + i * 4);
    bf16x4 b0 = *(const bf16x4*)(Yb + (size_t)p0 * DDIM + i * 4);
    bf16x4 a1 = *(const bf16x4*)(Ya + (size_t)p1 * DDIM + i * 4);
    bf16x4 b1 = *(const bf16x4*)(Yb + (size_t)p1 * DDIM + i * 4);
    float4 o;
    o.x = w0 * ((float)a0.x + (float)b0.x) + w1 * ((float)a1.x + (float)b1.x);
    o.y = w0 * ((float)a0.y + (float)b0.y) + w1 * ((float)a1.y + (float)b1.y);
    o.z = w0 * ((float)a0.z + (float)b0.z) + w1 * ((float)a1.z + (float)b1.z);
    o.w = w0 * ((float)a0.w + (float)b0.w) + w1 * ((float)a1.w + (float)b1.w);
    *(float4*)(out + (size_t)t * DDIM + i * 4) = o;
}

extern "C" void kernel_launch(void* const* d_in, const int* in_sizes, int n_in,
                              void* d_out, int out_size, void* d_ws, size_t ws_size,
                              hipStream_t stream) {
    const float* x      = (const float*)d_in[0];
    const float* gate_w = (const float*)d_in[1];
    const float* ebias  = (const float*)d_in[2];
    const float* wgp    = (const float*)d_in[3];
    const float* wup    = (const float*)d_in[4];
    const float* wdp    = (const float*)d_in[5];
    float* out = (float*)d_out;

    int*   ctrl     = (int*)d_ws;                          // 128 ints
    int*   tok_e    = ctrl + 128;                          // 2T
    float* tok_w    = (float*)(tok_e + 2 * T_TOK);         // 2T
    int*   pair_tok = (int*)(tok_w + 2 * T_TOK);           // RMAX
    int*   tok_pos  = pair_tok + RMAX;                     // 2T
    int*   cpart    = tok_pos + 2 * T_TOK;                 // RBLK*8 ints
    float* zpart    = (float*)(cpart + RBLK * NEXP);       // RBLK floats
    bf16*  Xg       = (bf16*)(zpart + RBLK);               // RMAX*768 (reused as Ya)
    bf16*  Ya       = Xg;
    bf16*  Yb       = Xg + (size_t)RMAX * DDIM;            // RMAX*768
    bf16*  G        = Yb + (size_t)RMAX * DDIM;            // RMAX*2688
    bf16*  WgT      = G + (size_t)RMAX * HDIM;
    bf16*  WuT      = WgT + (size_t)NEXP * DDIM * HDIM;
    bf16*  WdT      = WuT + (size_t)NEXP * DDIM * HDIM;

    hipMemsetAsync(out + (size_t)T_TOK * DDIM, 0, sizeof(float), stream);  // z_loss
    hipMemsetAsync(d_ws, 0, 512, stream);                                  // ctrl

    prep_kernel<<<TBLK + RBLK, 256, 0, stream>>>(wgp, wup, wdp, WgT, WuT, WdT,
                                                 x, gate_w, ebias, tok_e, tok_w, cpart, zpart);
    setup_kernel<<<1, 1024, 0, stream>>>(ctrl, cpart, zpart, tok_e, pair_tok, tok_pos,
                                         out + (size_t)T_TOK * DDIM);
    gather_kernel<<<RMAX, 192, 0, stream>>>(x, ctrl, pair_tok, Xg);
    gemm1_kernel<<<NMT * NT1, 256, 65536, stream>>>(Xg, WgT, WuT, ctrl, G);
    gemm2_kernel<<<NMT * NT2 * 2, 256, 65536, stream>>>(G, WdT, ctrl, Ya, Yb);
    combine_kernel<<<T_TOK, 192, 0, stream>>>(Ya, Yb, tok_pos, tok_w, out);
}